// Round 1
// baseline (13435.333 us; speedup 1.0000x reference)
//
#include <hip/hip_runtime.h>
#include <math.h>

#define NEG_SLOPE 0.2f

__device__ __forceinline__ float lrelu(float x) { return x > 0.f ? x : NEG_SLOPE * x; }

// float atomic max via monotone int/uint bit-pattern ordering (init must be -inf)
__device__ __forceinline__ void atomicMaxF(float* addr, float v) {
    if (v >= 0.f) atomicMax((int*)addr, __float_as_int(v));
    else          atomicMin((unsigned int*)addr, __float_as_uint(v));
}

// h[n][j] = sum_k x[n][k] * W[j][k], W row-major [64][K]
template <int K>
__global__ __launch_bounds__(256) void gemm_xwT(const float* __restrict__ x,
                                                const float* __restrict__ W,
                                                float* __restrict__ h, int N) {
    __shared__ float ws[64 * (K + 1)];   // +1 pad: 2-way LDS aliasing only (free)
    __shared__ float xs[16 * K];
    const int tid = threadIdx.x;
    const int n0 = blockIdx.x * 16;

    for (int idx = tid; idx < 64 * K; idx += 256) {
        int r = idx / K, c = idx - r * K;
        ws[r * (K + 1) + c] = W[idx];
    }
    for (int idx = tid; idx < 16 * K; idx += 256) {
        int nl = idx / K, c = idx - nl * K;
        int n = n0 + nl;
        xs[idx] = (n < N) ? x[(size_t)n * K + c] : 0.f;
    }
    __syncthreads();

    const int j = tid & 63, nn = tid >> 6;
    const float* wr = &ws[j * (K + 1)];
    const float* x0 = &xs[(nn * 4 + 0) * K];
    const float* x1 = &xs[(nn * 4 + 1) * K];
    const float* x2p = &xs[(nn * 4 + 2) * K];
    const float* x3 = &xs[(nn * 4 + 3) * K];
    float a0 = 0.f, a1 = 0.f, a2 = 0.f, a3 = 0.f;
#pragma unroll
    for (int k = 0; k < K; ++k) {
        float w = wr[k];
        a0 += w * x0[k]; a1 += w * x1[k]; a2 += w * x2p[k]; a3 += w * x3[k];
    }
    const int nb = n0 + nn * 4;
    if (nb + 0 < N) h[(size_t)(nb + 0) * 64 + j] = a0;
    if (nb + 1 < N) h[(size_t)(nb + 1) * 64 + j] = a1;
    if (nb + 2 < N) h[(size_t)(nb + 2) * 64 + j] = a2;
    if (nb + 3 < N) h[(size_t)(nb + 3) * 64 + j] = a3;
}

// per (node, head): e_src/e_dst dot products over 16 channels
__global__ void attn_coef(const float* __restrict__ h, const float* __restrict__ a_src,
                          const float* __restrict__ a_dst, float* __restrict__ e_src,
                          float* __restrict__ e_dst, int N) {
    int t = blockIdx.x * 256 + threadIdx.x;
    if (t >= N * 4) return;
    int n = t >> 2, hd = t & 3;
    const float* hp = h + (size_t)n * 64 + hd * 16;
    const float* as = a_src + hd * 16;
    const float* ad = a_dst + hd * 16;
    float es = 0.f, ed = 0.f;
#pragma unroll
    for (int c = 0; c < 16; ++c) { float v = hp[c]; es += v * as[c]; ed += v * ad[c]; }
    e_src[t] = es;
    e_dst[t] = ed;
}

__global__ void init_layer(float* __restrict__ amax, float* __restrict__ denom,
                           float* __restrict__ acc, int N) {
    int t = blockIdx.x * 256 + threadIdx.x;
    if (t < N * 64) acc[t] = 0.f;
    if (t < N * 4) { amax[t] = -INFINITY; denom[t] = 0.f; }
}

__global__ void edge_max(const int* __restrict__ src, const int* __restrict__ dst,
                         const float* __restrict__ e_src, const float* __restrict__ e_dst,
                         float* __restrict__ amax, int E, int Etot) {
    int e = blockIdx.x * 256 + threadIdx.x;
    if (e >= Etot) return;
    int s, d;
    if (e < E) { s = src[e]; d = dst[e]; } else { s = d = e - E; }
    const float4 es = *(const float4*)(e_src + (size_t)s * 4);
    const float4 ed = *(const float4*)(e_dst + (size_t)d * 4);
    atomicMaxF(&amax[d * 4 + 0], lrelu(es.x + ed.x));
    atomicMaxF(&amax[d * 4 + 1], lrelu(es.y + ed.y));
    atomicMaxF(&amax[d * 4 + 2], lrelu(es.z + ed.z));
    atomicMaxF(&amax[d * 4 + 3], lrelu(es.w + ed.w));
}

// per (edge, head): p = exp(lrelu(es+ed) - amax[d]); denom[d]+=p; acc[d] += p*h[s]
__global__ void edge_accum(const int* __restrict__ src, const int* __restrict__ dst,
                           const float* __restrict__ e_src, const float* __restrict__ e_dst,
                           const float* __restrict__ amax, float* __restrict__ denom,
                           const float* __restrict__ h, float* __restrict__ acc,
                           int E, int Etot) {
    int t = blockIdx.x * 256 + threadIdx.x;
    if (t >= Etot * 4) return;
    int e = t >> 2, hd = t & 3;
    int s, d;
    if (e < E) { s = src[e]; d = dst[e]; } else { s = d = e - E; }
    float a = lrelu(e_src[(size_t)s * 4 + hd] + e_dst[(size_t)d * 4 + hd]);
    float p = expf(a - amax[(size_t)d * 4 + hd]);
    unsafeAtomicAdd(&denom[(size_t)d * 4 + hd], p);
    const float4* hv = (const float4*)(h + (size_t)s * 64 + hd * 16);
    float* ap = acc + (size_t)d * 64 + hd * 16;
#pragma unroll
    for (int q = 0; q < 4; ++q) {
        float4 v = hv[q];
        unsafeAtomicAdd(ap + q * 4 + 0, p * v.x);
        unsafeAtomicAdd(ap + q * 4 + 1, p * v.y);
        unsafeAtomicAdd(ap + q * 4 + 2, p * v.z);
        unsafeAtomicAdd(ap + q * 4 + 3, p * v.w);
    }
}

// out[n][j] = elu(acc[n][j]/(denom[n][head]+1e-16) + b[j])
__global__ void epilogue(const float* __restrict__ acc, const float* __restrict__ denom,
                         const float* __restrict__ b, float* __restrict__ xo, int N) {
    int t = blockIdx.x * 256 + threadIdx.x;
    if (t >= N * 64) return;
    int n = t >> 6, j = t & 63, hd = j >> 4;
    float v = acc[t] / (denom[n * 4 + hd] + 1e-16f) + b[j];
    xo[t] = v > 0.f ? v : expf(v) - 1.f;
}

// one wave per node: out[n] = dot(x2[n][:64], fcw) + fcb
__global__ void fc_out(const float* __restrict__ x2, const float* __restrict__ fcw,
                       const float* __restrict__ fcb, float* __restrict__ out, int N) {
    int g = blockIdx.x * 256 + threadIdx.x;
    int n = g >> 6;
    int lane = threadIdx.x & 63;
    if (n >= N) return;
    float v = x2[(size_t)n * 64 + lane] * fcw[lane];
#pragma unroll
    for (int off = 32; off > 0; off >>= 1) v += __shfl_down(v, off, 64);
    if (lane == 0) out[n] = v + fcb[0];
}

extern "C" void kernel_launch(void* const* d_in, const int* in_sizes, int n_in,
                              void* d_out, int out_size, void* d_ws, size_t ws_size,
                              hipStream_t stream) {
    const float* x   = (const float*)d_in[0];
    const int*   ei  = (const int*)d_in[1];
    const float* w1  = (const float*)d_in[2];
    const float* as1 = (const float*)d_in[3];
    const float* ad1 = (const float*)d_in[4];
    const float* b1  = (const float*)d_in[5];
    const float* w2  = (const float*)d_in[6];
    const float* as2 = (const float*)d_in[7];
    const float* ad2 = (const float*)d_in[8];
    const float* b2  = (const float*)d_in[9];
    const float* fcw = (const float*)d_in[10];
    const float* fcb = (const float*)d_in[11];
    float* out = (float*)d_out;

    const int N = in_sizes[0] / 128;  // 100000
    const int E = in_sizes[1] / 2;    // 1600000
    const int Etot = E + N;           // with self-loops
    const int* src = ei;
    const int* dst = ei + E;

    float* ws    = (float*)d_ws;
    float* h     = ws;                        // N*64
    float* acc   = h + (size_t)N * 64;        // N*64
    float* x2    = acc + (size_t)N * 64;      // N*64
    float* e_src = x2 + (size_t)N * 64;       // N*4
    float* e_dst = e_src + (size_t)N * 4;     // N*4
    float* amax  = e_dst + (size_t)N * 4;     // N*4
    float* denom = amax + (size_t)N * 4;      // N*4

    dim3 blk(256);
    const int gN16 = (N + 15) / 16;
    const int gNH  = (N * 4 + 255) / 256;
    const int gN64 = (N * 64 + 255) / 256;
    const int gE   = (Etot + 255) / 256;
    const int gEH  = (Etot * 4 + 255) / 256;

    // ---- layer 1 ----
    gemm_xwT<128><<<gN16, blk, 0, stream>>>(x, w1, h, N);
    attn_coef<<<gNH, blk, 0, stream>>>(h, as1, ad1, e_src, e_dst, N);
    init_layer<<<gN64, blk, 0, stream>>>(amax, denom, acc, N);
    edge_max<<<gE, blk, 0, stream>>>(src, dst, e_src, e_dst, amax, E, Etot);
    edge_accum<<<gEH, blk, 0, stream>>>(src, dst, e_src, e_dst, amax, denom, h, acc, E, Etot);
    epilogue<<<gN64, blk, 0, stream>>>(acc, denom, b1, x2, N);

    // ---- layer 2 ----
    gemm_xwT<64><<<gN16, blk, 0, stream>>>(x2, w2, h, N);
    attn_coef<<<gNH, blk, 0, stream>>>(h, as2, ad2, e_src, e_dst, N);
    init_layer<<<gN64, blk, 0, stream>>>(amax, denom, acc, N);
    edge_max<<<gE, blk, 0, stream>>>(src, dst, e_src, e_dst, amax, E, Etot);
    edge_accum<<<gEH, blk, 0, stream>>>(src, dst, e_src, e_dst, amax, denom, h, acc, E, Etot);
    epilogue<<<gN64, blk, 0, stream>>>(acc, denom, b2, x2, N);

    // ---- final FC ----
    fc_out<<<(N * 64 + 255) / 256, blk, 0, stream>>>(x2, fcw, fcb, out, N);
}

// Round 2
// 760.582 us; speedup vs baseline: 17.6645x; 17.6645x over previous
//
#include <hip/hip_runtime.h>
#include <math.h>

#define NEG_SLOPE 0.2f

__device__ __forceinline__ float lrelu(float x) { return x > 0.f ? x : NEG_SLOPE * x; }

// ---------------- dense h = x @ W^T ----------------
// h[n][j] = sum_k x[n][k] * W[j][k], W row-major [64][K]
template <int K>
__global__ __launch_bounds__(256) void gemm_xwT(const float* __restrict__ x,
                                                const float* __restrict__ W,
                                                float* __restrict__ h, int N) {
    __shared__ float ws[64 * (K + 1)];
    __shared__ float xs[16 * K];
    const int tid = threadIdx.x;
    const int n0 = blockIdx.x * 16;

    for (int idx = tid; idx < 64 * K; idx += 256) {
        int r = idx / K, c = idx - r * K;
        ws[r * (K + 1) + c] = W[idx];
    }
    for (int idx = tid; idx < 16 * K; idx += 256) {
        int nl = idx / K, c = idx - nl * K;
        int n = n0 + nl;
        xs[idx] = (n < N) ? x[(size_t)n * K + c] : 0.f;
    }
    __syncthreads();

    const int j = tid & 63, nn = tid >> 6;
    const float* wr = &ws[j * (K + 1)];
    const float* x0 = &xs[(nn * 4 + 0) * K];
    const float* x1 = &xs[(nn * 4 + 1) * K];
    const float* x2p = &xs[(nn * 4 + 2) * K];
    const float* x3 = &xs[(nn * 4 + 3) * K];
    float a0 = 0.f, a1 = 0.f, a2 = 0.f, a3 = 0.f;
#pragma unroll
    for (int k = 0; k < K; ++k) {
        float w = wr[k];
        a0 += w * x0[k]; a1 += w * x1[k]; a2 += w * x2p[k]; a3 += w * x3[k];
    }
    const int nb = n0 + nn * 4;
    if (nb + 0 < N) h[(size_t)(nb + 0) * 64 + j] = a0;
    if (nb + 1 < N) h[(size_t)(nb + 1) * 64 + j] = a1;
    if (nb + 2 < N) h[(size_t)(nb + 2) * 64 + j] = a2;
    if (nb + 3 < N) h[(size_t)(nb + 3) * 64 + j] = a3;
}

// per (node, head): e_src/e_dst dot products over 16 channels
__global__ void attn_coef(const float* __restrict__ h, const float* __restrict__ a_src,
                          const float* __restrict__ a_dst, float* __restrict__ e_src,
                          float* __restrict__ e_dst, int N) {
    int t = blockIdx.x * 256 + threadIdx.x;
    if (t >= N * 4) return;
    int n = t >> 2, hd = t & 3;
    const float* hp = h + (size_t)n * 64 + hd * 16;
    const float* as = a_src + hd * 16;
    const float* ad = a_dst + hd * 16;
    float es = 0.f, ed = 0.f;
#pragma unroll
    for (int c = 0; c < 16; ++c) { float v = hp[c]; es += v * as[c]; ed += v * ad[c]; }
    e_src[t] = es;
    e_dst[t] = ed;
}

// ---------------- CSR build (dst -> incoming edges) ----------------
__global__ void csr_count(const int* __restrict__ dst, int* __restrict__ counts,
                          int E, int Etot) {
    int e = blockIdx.x * 256 + threadIdx.x;
    if (e >= Etot) return;
    int d = (e < E) ? dst[e] : e - E;
    atomicAdd(&counts[d], 1);
}

// per-block inclusive scan of counts (256/block); block totals to bsum
__global__ void scan_l1(const int* __restrict__ counts, int* __restrict__ incl,
                        int* __restrict__ bsum, int N) {
    __shared__ int s[256];
    int tid = threadIdx.x;
    int i = blockIdx.x * 256 + tid;
    int v = (i < N) ? counts[i] : 0;
    s[tid] = v; __syncthreads();
#pragma unroll
    for (int off = 1; off < 256; off <<= 1) {
        int t = (tid >= off) ? s[tid - off] : 0;
        __syncthreads();
        s[tid] += t;
        __syncthreads();
    }
    if (i < N) incl[i] = s[tid];
    if (tid == 255) bsum[blockIdx.x] = s[255];
}

// exclusive scan of block sums (single block, NB <= 512)
__global__ void scan_l2(int* __restrict__ bsum, int NB) {
    __shared__ int s[512];
    int tid = threadIdx.x;
    int v = (tid < NB) ? bsum[tid] : 0;
    s[tid] = v; __syncthreads();
#pragma unroll
    for (int off = 1; off < 512; off <<= 1) {
        int t = (tid >= off) ? s[tid - off] : 0;
        __syncthreads();
        s[tid] += t;
        __syncthreads();
    }
    if (tid < NB) bsum[tid] = s[tid] - v;  // exclusive
}

// offs/cursor = exclusive prefix (same grid mapping as scan_l1)
__global__ void scan_fin(const int* __restrict__ counts, const int* __restrict__ incl,
                         const int* __restrict__ bsum, int* __restrict__ offs,
                         int* __restrict__ cursor, int N) {
    int i = blockIdx.x * 256 + threadIdx.x;
    if (i >= N) return;
    int e = incl[i] - counts[i] + bsum[blockIdx.x];
    offs[i] = e;
    cursor[i] = e;
}

__global__ void csr_scatter(const int* __restrict__ src, const int* __restrict__ dst,
                            int* __restrict__ cursor, int* __restrict__ col,
                            int E, int Etot) {
    int e = blockIdx.x * 256 + threadIdx.x;
    if (e >= Etot) return;
    int s, d;
    if (e < E) { s = src[e]; d = dst[e]; } else { s = d = e - E; }
    int pos = atomicAdd(&cursor[d], 1);
    col[pos] = s;
}

// ---------------- fused gather: online softmax + aggregate + epilogue ----------------
// one wave per dst node; lane = (head<<4)|channel
__global__ __launch_bounds__(256) void gat_gather(const int* __restrict__ offs,
                                                  const int* __restrict__ counts,
                                                  const int* __restrict__ col,
                                                  const float* __restrict__ es,
                                                  const float* __restrict__ ed,
                                                  const float* __restrict__ h,
                                                  const float* __restrict__ b,
                                                  float* __restrict__ xo, int N) {
    int w = (blockIdx.x * 256 + threadIdx.x) >> 6;  // node
    if (w >= N) return;
    int lane = threadIdx.x & 63, hd = lane >> 4;
    int beg = offs[w], cnt = counts[w];
    float edv = ed[(size_t)w * 4 + hd];
    float m = -INFINITY, l = 0.f, acc = 0.f;
    for (int base = 0; base < cnt; base += 64) {
        int k = base + lane;
        int myS = (k < cnt) ? col[beg + k] : 0;
        int lim = min(64, cnt - base);
        for (int j = 0; j < lim; ++j) {
            int s = __shfl(myS, j, 64);
            float a = es[(size_t)s * 4 + hd] + edv;
            a = a > 0.f ? a : NEG_SLOPE * a;
            float mn = fmaxf(m, a);
            float sc = expf(m - mn);
            float p = expf(a - mn);
            float hv = h[(size_t)s * 64 + lane];
            acc = acc * sc + p * hv;
            l = l * sc + p;
            m = mn;
        }
    }
    float v = acc / (l + 1e-16f) + b[lane];
    xo[(size_t)w * 64 + lane] = v > 0.f ? v : expf(v) - 1.f;
}

// one wave per node: out[n] = dot(x2[n][:64], fcw) + fcb
__global__ void fc_out(const float* __restrict__ x2, const float* __restrict__ fcw,
                       const float* __restrict__ fcb, float* __restrict__ out, int N) {
    int g = blockIdx.x * 256 + threadIdx.x;
    int n = g >> 6;
    int lane = threadIdx.x & 63;
    if (n >= N) return;
    float v = x2[(size_t)n * 64 + lane] * fcw[lane];
#pragma unroll
    for (int off = 32; off > 0; off >>= 1) v += __shfl_down(v, off, 64);
    if (lane == 0) out[n] = v + fcb[0];
}

extern "C" void kernel_launch(void* const* d_in, const int* in_sizes, int n_in,
                              void* d_out, int out_size, void* d_ws, size_t ws_size,
                              hipStream_t stream) {
    const float* x   = (const float*)d_in[0];
    const int*   ei  = (const int*)d_in[1];
    const float* w1  = (const float*)d_in[2];
    const float* as1 = (const float*)d_in[3];
    const float* ad1 = (const float*)d_in[4];
    const float* b1  = (const float*)d_in[5];
    const float* w2  = (const float*)d_in[6];
    const float* as2 = (const float*)d_in[7];
    const float* ad2 = (const float*)d_in[8];
    const float* b2  = (const float*)d_in[9];
    const float* fcw = (const float*)d_in[10];
    const float* fcb = (const float*)d_in[11];
    float* out = (float*)d_out;

    const int N = in_sizes[0] / 128;  // 100000
    const int E = in_sizes[1] / 2;    // 1600000
    const int Etot = E + N;
    const int* src = ei;
    const int* dst = ei + E;

    char* p = (char*)d_ws;
    float* h     = (float*)p;  p += (size_t)N * 64 * 4;
    float* x2    = (float*)p;  p += (size_t)N * 64 * 4;
    float* es    = (float*)p;  p += (size_t)N * 4 * 4;
    float* ed    = (float*)p;  p += (size_t)N * 4 * 4;
    int* counts  = (int*)p;    p += (size_t)N * 4;
    int* incl    = (int*)p;    p += (size_t)N * 4;
    int* offs    = (int*)p;    p += (size_t)N * 4;
    int* cursor  = (int*)p;    p += (size_t)N * 4;
    int* col     = (int*)p;    p += (size_t)Etot * 4;
    int* bsum    = (int*)p;    p += 512 * 4;

    dim3 blk(256);
    const int NB   = (N + 255) / 256;       // 391 (<=512 required)
    const int gN16 = (N + 15) / 16;
    const int gNH  = (N * 4 + 255) / 256;
    const int gE   = (Etot + 255) / 256;
    const int gW   = (N * 64 + 255) / 256;  // wave-per-node kernels

    // ---- CSR build (once, shared by both layers) ----
    hipMemsetAsync(counts, 0, (size_t)N * 4, stream);
    csr_count<<<gE, blk, 0, stream>>>(dst, counts, E, Etot);
    scan_l1<<<NB, blk, 0, stream>>>(counts, incl, bsum, N);
    scan_l2<<<1, 512, 0, stream>>>(bsum, NB);
    scan_fin<<<NB, blk, 0, stream>>>(counts, incl, bsum, offs, cursor, N);
    csr_scatter<<<gE, blk, 0, stream>>>(src, dst, cursor, col, E, Etot);

    // ---- layer 1 ----
    gemm_xwT<128><<<gN16, blk, 0, stream>>>(x, w1, h, N);
    attn_coef<<<gNH, blk, 0, stream>>>(h, as1, ad1, es, ed, N);
    gat_gather<<<gW, blk, 0, stream>>>(offs, counts, col, es, ed, h, b1, x2, N);

    // ---- layer 2 ----
    gemm_xwT<64><<<gN16, blk, 0, stream>>>(x2, w2, h, N);
    attn_coef<<<gNH, blk, 0, stream>>>(h, as2, ad2, es, ed, N);
    gat_gather<<<gW, blk, 0, stream>>>(offs, counts, col, es, ed, h, b2, x2, N);

    // ---- final FC ----
    fc_out<<<gW, blk, 0, stream>>>(x2, fcw, fcb, out, N);
}

// Round 3
// 450.947 us; speedup vs baseline: 29.7936x; 1.6866x over previous
//
#include <hip/hip_runtime.h>
#include <math.h>

#define NEG_SLOPE 0.2f

__device__ __forceinline__ float lrelu(float x) { return x > 0.f ? x : NEG_SLOPE * x; }

// ---------------- dense h = x @ W^T ----------------
// 64x64 tile per block, 4x4 per thread, k-major LDS staging.
// x: [N][K] row-major, W: [64][K] row-major, h: [N][64]
template <int K>
__global__ __launch_bounds__(256) void gemm_tile(const float* __restrict__ x,
                                                 const float* __restrict__ W,
                                                 float* __restrict__ h, int N) {
    constexpr int CK = 32;
    __shared__ float xs[CK][68];  // [k][node]  (68: 16B-aligned rows + bank spread)
    __shared__ float ws[CK][68];  // [k][col]
    const int tid = threadIdx.x;
    const int n0 = blockIdx.x * 64;
    const int tx = tid & 15, ty = tid >> 4;

    float acc[4][4] = {};

    for (int k0 = 0; k0 < K; k0 += CK) {
#pragma unroll
        for (int i = 0; i < 2; ++i) {
            int slot = tid + i * 256;  // 0..511
            int nl = slot >> 3;        // 0..63
            int kq = slot & 7;         // float4 index within 32-k chunk
            int n = n0 + nl;
            float4 v = (n < N) ? *(const float4*)(x + (size_t)n * K + k0 + kq * 4)
                               : make_float4(0.f, 0.f, 0.f, 0.f);
            xs[kq * 4 + 0][nl] = v.x; xs[kq * 4 + 1][nl] = v.y;
            xs[kq * 4 + 2][nl] = v.z; xs[kq * 4 + 3][nl] = v.w;
            float4 wv = *(const float4*)(W + (size_t)nl * K + k0 + kq * 4);
            ws[kq * 4 + 0][nl] = wv.x; ws[kq * 4 + 1][nl] = wv.y;
            ws[kq * 4 + 2][nl] = wv.z; ws[kq * 4 + 3][nl] = wv.w;
        }
        __syncthreads();
#pragma unroll
        for (int k = 0; k < CK; ++k) {
            float4 xv = *(const float4*)(&xs[k][ty * 4]);
            float4 wv = *(const float4*)(&ws[k][tx * 4]);
            float xa[4] = {xv.x, xv.y, xv.z, xv.w};
            float wa[4] = {wv.x, wv.y, wv.z, wv.w};
#pragma unroll
            for (int a = 0; a < 4; ++a)
#pragma unroll
                for (int c = 0; c < 4; ++c)
                    acc[a][c] += xa[a] * wa[c];
        }
        __syncthreads();
    }
#pragma unroll
    for (int a = 0; a < 4; ++a) {
        int n = n0 + ty * 4 + a;
        if (n < N)
            *(float4*)(h + (size_t)n * 64 + tx * 4) =
                make_float4(acc[a][0], acc[a][1], acc[a][2], acc[a][3]);
    }
}

// per (node, head): e_src/e_dst dot products over 16 channels
__global__ void attn_coef(const float* __restrict__ h, const float* __restrict__ a_src,
                          const float* __restrict__ a_dst, float* __restrict__ e_src,
                          float* __restrict__ e_dst, int N) {
    int t = blockIdx.x * 256 + threadIdx.x;
    if (t >= N * 4) return;
    int n = t >> 2, hd = t & 3;
    const float4* hp = (const float4*)(h + (size_t)n * 64 + hd * 16);
    const float4* as = (const float4*)(a_src + hd * 16);
    const float4* ad = (const float4*)(a_dst + hd * 16);
    float es = 0.f, ed = 0.f;
#pragma unroll
    for (int q = 0; q < 4; ++q) {
        float4 hv = hp[q], av = as[q], dv = ad[q];
        es += hv.x * av.x + hv.y * av.y + hv.z * av.z + hv.w * av.w;
        ed += hv.x * dv.x + hv.y * dv.y + hv.z * dv.z + hv.w * dv.w;
    }
    e_src[t] = es;
    e_dst[t] = ed;
}

// ---------------- CSR build (dst -> incoming edges) ----------------
__global__ void csr_count(const int* __restrict__ dst, int* __restrict__ counts,
                          int E, int Etot) {
    int e = blockIdx.x * 256 + threadIdx.x;
    if (e >= Etot) return;
    int d = (e < E) ? dst[e] : e - E;
    atomicAdd(&counts[d], 1);
}

__global__ void scan_l1(const int* __restrict__ counts, int* __restrict__ incl,
                        int* __restrict__ bsum, int N) {
    __shared__ int s[256];
    int tid = threadIdx.x;
    int i = blockIdx.x * 256 + tid;
    int v = (i < N) ? counts[i] : 0;
    s[tid] = v; __syncthreads();
#pragma unroll
    for (int off = 1; off < 256; off <<= 1) {
        int t = (tid >= off) ? s[tid - off] : 0;
        __syncthreads();
        s[tid] += t;
        __syncthreads();
    }
    if (i < N) incl[i] = s[tid];
    if (tid == 255) bsum[blockIdx.x] = s[255];
}

__global__ void scan_l2(int* __restrict__ bsum, int NB) {
    __shared__ int s[512];
    int tid = threadIdx.x;
    int v = (tid < NB) ? bsum[tid] : 0;
    s[tid] = v; __syncthreads();
#pragma unroll
    for (int off = 1; off < 512; off <<= 1) {
        int t = (tid >= off) ? s[tid - off] : 0;
        __syncthreads();
        s[tid] += t;
        __syncthreads();
    }
    if (tid < NB) bsum[tid] = s[tid] - v;
}

__global__ void scan_fin(const int* __restrict__ counts, const int* __restrict__ incl,
                         const int* __restrict__ bsum, int* __restrict__ offs,
                         int* __restrict__ cursor, int N) {
    int i = blockIdx.x * 256 + threadIdx.x;
    if (i >= N) return;
    int e = incl[i] - counts[i] + bsum[blockIdx.x];
    offs[i] = e;
    cursor[i] = e;
}

__global__ void csr_scatter(const int* __restrict__ src, const int* __restrict__ dst,
                            int* __restrict__ cursor, int* __restrict__ col,
                            int E, int Etot) {
    int e = blockIdx.x * 256 + threadIdx.x;
    if (e >= Etot) return;
    int s, d;
    if (e < E) { s = src[e]; d = dst[e]; } else { s = d = e - E; }
    int pos = atomicAdd(&cursor[d], 1);
    col[pos] = s;
}

// ---------------- fused gather: softmax (no-max form) + aggregate + epilogue ----------
// one wave per dst node; lane = (head<<4)|channel.
// logits are bounded (|a| < ~10) so exp(a) is safe without max subtraction;
// result identical to max-subtracted softmax.
__global__ __launch_bounds__(256) void gat_gather(const int* __restrict__ offs,
                                                  const int* __restrict__ counts,
                                                  const int* __restrict__ col,
                                                  const float* __restrict__ es,
                                                  const float* __restrict__ ed,
                                                  const float* __restrict__ h,
                                                  const float* __restrict__ b,
                                                  float* __restrict__ xo, int N) {
    int w = (blockIdx.x * 256 + threadIdx.x) >> 6;
    if (w >= N) return;
    int lane = threadIdx.x & 63, hd = lane >> 4;
    int beg = offs[w], cnt = counts[w];
    float edv = ed[(size_t)w * 4 + hd];
    float l = 0.f, acc = 0.f;
    int j = 0;
    for (; j + 4 <= cnt; j += 4) {
        int s0 = col[beg + j + 0], s1 = col[beg + j + 1];
        int s2 = col[beg + j + 2], s3 = col[beg + j + 3];
        float a0 = lrelu(es[(size_t)s0 * 4 + hd] + edv);
        float a1 = lrelu(es[(size_t)s1 * 4 + hd] + edv);
        float a2 = lrelu(es[(size_t)s2 * 4 + hd] + edv);
        float a3 = lrelu(es[(size_t)s3 * 4 + hd] + edv);
        float h0 = h[(size_t)s0 * 64 + lane];
        float h1 = h[(size_t)s1 * 64 + lane];
        float h2 = h[(size_t)s2 * 64 + lane];
        float h3 = h[(size_t)s3 * 64 + lane];
        float p0 = expf(a0), p1 = expf(a1), p2 = expf(a2), p3 = expf(a3);
        l += (p0 + p1) + (p2 + p3);
        acc += p0 * h0 + p1 * h1 + p2 * h2 + p3 * h3;
    }
    for (; j < cnt; ++j) {
        int s = col[beg + j];
        float a = lrelu(es[(size_t)s * 4 + hd] + edv);
        float p = expf(a);
        l += p;
        acc += p * h[(size_t)s * 64 + lane];
    }
    float v = acc / (l + 1e-16f) + b[lane];
    xo[(size_t)w * 64 + lane] = v > 0.f ? v : expf(v) - 1.f;
}

// one wave per node: out[n] = dot(x2[n][:64], fcw) + fcb
__global__ void fc_out(const float* __restrict__ x2, const float* __restrict__ fcw,
                       const float* __restrict__ fcb, float* __restrict__ out, int N) {
    int g = blockIdx.x * 256 + threadIdx.x;
    int n = g >> 6;
    int lane = threadIdx.x & 63;
    if (n >= N) return;
    float v = x2[(size_t)n * 64 + lane] * fcw[lane];
#pragma unroll
    for (int off = 32; off > 0; off >>= 1) v += __shfl_down(v, off, 64);
    if (lane == 0) out[n] = v + fcb[0];
}

extern "C" void kernel_launch(void* const* d_in, const int* in_sizes, int n_in,
                              void* d_out, int out_size, void* d_ws, size_t ws_size,
                              hipStream_t stream) {
    const float* x   = (const float*)d_in[0];
    const int*   ei  = (const int*)d_in[1];
    const float* w1  = (const float*)d_in[2];
    const float* as1 = (const float*)d_in[3];
    const float* ad1 = (const float*)d_in[4];
    const float* b1  = (const float*)d_in[5];
    const float* w2  = (const float*)d_in[6];
    const float* as2 = (const float*)d_in[7];
    const float* ad2 = (const float*)d_in[8];
    const float* b2  = (const float*)d_in[9];
    const float* fcw = (const float*)d_in[10];
    const float* fcb = (const float*)d_in[11];
    float* out = (float*)d_out;

    const int N = in_sizes[0] / 128;  // 100000
    const int E = in_sizes[1] / 2;    // 1600000
    const int Etot = E + N;
    const int* src = ei;
    const int* dst = ei + E;

    char* p = (char*)d_ws;
    float* h     = (float*)p;  p += (size_t)N * 64 * 4;
    float* x2    = (float*)p;  p += (size_t)N * 64 * 4;
    float* es    = (float*)p;  p += (size_t)N * 4 * 4;
    float* ed    = (float*)p;  p += (size_t)N * 4 * 4;
    int* counts  = (int*)p;    p += (size_t)N * 4;
    int* incl    = (int*)p;    p += (size_t)N * 4;
    int* offs    = (int*)p;    p += (size_t)N * 4;
    int* cursor  = (int*)p;    p += (size_t)N * 4;
    int* col     = (int*)p;    p += (size_t)Etot * 4;
    int* bsum    = (int*)p;    p += 512 * 4;

    dim3 blk(256);
    const int NB   = (N + 255) / 256;       // 391 (<=512)
    const int gN64t = (N + 63) / 64;        // gemm tiles
    const int gNH  = (N * 4 + 255) / 256;
    const int gE   = (Etot + 255) / 256;
    const int gW   = (N * 64 + 255) / 256;  // wave-per-node kernels

    // ---- CSR build (once, shared by both layers) ----
    hipMemsetAsync(counts, 0, (size_t)N * 4, stream);
    csr_count<<<gE, blk, 0, stream>>>(dst, counts, E, Etot);
    scan_l1<<<NB, blk, 0, stream>>>(counts, incl, bsum, N);
    scan_l2<<<1, 512, 0, stream>>>(bsum, NB);
    scan_fin<<<NB, blk, 0, stream>>>(counts, incl, bsum, offs, cursor, N);
    csr_scatter<<<gE, blk, 0, stream>>>(src, dst, cursor, col, E, Etot);

    // ---- layer 1 ----
    gemm_tile<128><<<gN64t, blk, 0, stream>>>(x, w1, h, N);
    attn_coef<<<gNH, blk, 0, stream>>>(h, as1, ad1, es, ed, N);
    gat_gather<<<gW, blk, 0, stream>>>(offs, counts, col, es, ed, h, b1, x2, N);

    // ---- layer 2 ----
    gemm_tile<64><<<gN64t, blk, 0, stream>>>(x2, w2, h, N);
    attn_coef<<<gNH, blk, 0, stream>>>(h, as2, ad2, es, ed, N);
    gat_gather<<<gW, blk, 0, stream>>>(offs, counts, col, es, ed, h, b2, x2, N);

    // ---- final FC ----
    fc_out<<<gW, blk, 0, stream>>>(x2, fcw, fcb, out, N);
}

// Round 4
// 298.220 us; speedup vs baseline: 45.0517x; 1.5121x over previous
//
#include <hip/hip_runtime.h>
#include <math.h>

#define NEG_SLOPE 0.2f
#define BSH 8              // 256 nodes per bucket
#define CAPB 6144          // phase-B LDS capacity (entries); mean ~4352

__device__ __forceinline__ float lrelu(float x) { return x > 0.f ? x : NEG_SLOPE * x; }

// ---------------- dense h = x @ W^T ----------------
// 64x64 tile per block, 4x4 per thread, k-major LDS staging.
template <int K>
__global__ __launch_bounds__(256) void gemm_tile(const float* __restrict__ x,
                                                 const float* __restrict__ W,
                                                 float* __restrict__ h, int N) {
    constexpr int CK = 32;
    __shared__ float xs[CK][68];
    __shared__ float ws[CK][68];
    const int tid = threadIdx.x;
    const int n0 = blockIdx.x * 64;
    const int tx = tid & 15, ty = tid >> 4;

    float acc[4][4] = {};

    for (int k0 = 0; k0 < K; k0 += CK) {
#pragma unroll
        for (int i = 0; i < 2; ++i) {
            int slot = tid + i * 256;
            int nl = slot >> 3;
            int kq = slot & 7;
            int n = n0 + nl;
            float4 v = (n < N) ? *(const float4*)(x + (size_t)n * K + k0 + kq * 4)
                               : make_float4(0.f, 0.f, 0.f, 0.f);
            xs[kq * 4 + 0][nl] = v.x; xs[kq * 4 + 1][nl] = v.y;
            xs[kq * 4 + 2][nl] = v.z; xs[kq * 4 + 3][nl] = v.w;
            float4 wv = *(const float4*)(W + (size_t)nl * K + k0 + kq * 4);
            ws[kq * 4 + 0][nl] = wv.x; ws[kq * 4 + 1][nl] = wv.y;
            ws[kq * 4 + 2][nl] = wv.z; ws[kq * 4 + 3][nl] = wv.w;
        }
        __syncthreads();
#pragma unroll
        for (int k = 0; k < CK; ++k) {
            float4 xv = *(const float4*)(&xs[k][ty * 4]);
            float4 wv = *(const float4*)(&ws[k][tx * 4]);
            float xa[4] = {xv.x, xv.y, xv.z, xv.w};
            float wa[4] = {wv.x, wv.y, wv.z, wv.w};
#pragma unroll
            for (int a = 0; a < 4; ++a)
#pragma unroll
                for (int c = 0; c < 4; ++c)
                    acc[a][c] += xa[a] * wa[c];
        }
        __syncthreads();
    }
#pragma unroll
    for (int a = 0; a < 4; ++a) {
        int n = n0 + ty * 4 + a;
        if (n < N)
            *(float4*)(h + (size_t)n * 64 + tx * 4) =
                make_float4(acc[a][0], acc[a][1], acc[a][2], acc[a][3]);
    }
}

// per (node, head): e_src/e_dst dot products over 16 channels
__global__ void attn_coef(const float* __restrict__ h, const float* __restrict__ a_src,
                          const float* __restrict__ a_dst, float* __restrict__ e_src,
                          float* __restrict__ e_dst, int N) {
    int t = blockIdx.x * 256 + threadIdx.x;
    if (t >= N * 4) return;
    int n = t >> 2, hd = t & 3;
    const float4* hp = (const float4*)(h + (size_t)n * 64 + hd * 16);
    const float4* as = (const float4*)(a_src + hd * 16);
    const float4* ad = (const float4*)(a_dst + hd * 16);
    float es = 0.f, ed = 0.f;
#pragma unroll
    for (int q = 0; q < 4; ++q) {
        float4 hv = hp[q], av = as[q], dv = ad[q];
        es += hv.x * av.x + hv.y * av.y + hv.z * av.z + hv.w * av.w;
        ed += hv.x * dv.x + hv.y * dv.y + hv.z * dv.z + hv.w * dv.w;
    }
    e_src[t] = es;
    e_dst[t] = ed;
}

// ---------------- CSR build: LDS bucket sort (no global atomics) ----------------
// Phase A1: per-block histogram over dst>>BSH buckets
__global__ __launch_bounds__(256) void bucket_hist(const int* __restrict__ dst,
                                                   int* __restrict__ hist_g,
                                                   int E, int Etot, int NBUCK, int nIter) {
    __shared__ int hist[512];
    int blk = blockIdx.x, tid = threadIdx.x;
    for (int i = tid; i < NBUCK; i += 256) hist[i] = 0;
    __syncthreads();
    int base = blk * nIter * 256;
    for (int i = 0; i < nIter; ++i) {
        int e = base + i * 256 + tid;
        if (e < Etot) {
            int d = (e < E) ? dst[e] : e - E;
            atomicAdd(&hist[d >> BSH], 1);
        }
    }
    __syncthreads();
    for (int i = tid; i < NBUCK; i += 256) hist_g[(size_t)blk * NBUCK + i] = hist[i];
}

// Phase A2: per-bucket exclusive scan over blocks (one block per bucket, NBLK<=256)
__global__ __launch_bounds__(256) void bucket_scan_blocks(int* __restrict__ hist_g,
                                                          int* __restrict__ tot,
                                                          int NBUCK, int NBLK) {
    __shared__ int s[256];
    int b = blockIdx.x, tid = threadIdx.x;
    int v = (tid < NBLK) ? hist_g[(size_t)tid * NBUCK + b] : 0;
    s[tid] = v; __syncthreads();
#pragma unroll
    for (int off = 1; off < 256; off <<= 1) {
        int t = (tid >= off) ? s[tid - off] : 0;
        __syncthreads();
        s[tid] += t;
        __syncthreads();
    }
    if (tid < NBLK) hist_g[(size_t)tid * NBUCK + b] = s[tid] - v;  // exclusive
    if (tid == 255) tot[b] = s[255];
}

// Phase A3: exclusive scan of bucket totals (1 block, NBUCK<=512); also offs[N]=Etot
__global__ void bucket_scan_tot(const int* __restrict__ tot, int* __restrict__ bbase,
                                int* __restrict__ offs, int NBUCK, int Etot, int N) {
    __shared__ int s[512];
    int tid = threadIdx.x;
    int v = (tid < NBUCK) ? tot[tid] : 0;
    s[tid] = v; __syncthreads();
#pragma unroll
    for (int off = 1; off < 512; off <<= 1) {
        int t = (tid >= off) ? s[tid - off] : 0;
        __syncthreads();
        s[tid] += t;
        __syncthreads();
    }
    if (tid < NBUCK) bbase[tid] = s[tid] - v;
    if (tid == 0) offs[N] = Etot;
}

// Phase A4: scatter edges into bucket-grouped buffer via LDS cursors
__global__ __launch_bounds__(256) void bucket_scatter(const int* __restrict__ src,
                                                      const int* __restrict__ dst,
                                                      const int* __restrict__ hist_g,
                                                      const int* __restrict__ bbase,
                                                      unsigned int* __restrict__ bbuf,
                                                      int E, int Etot, int NBUCK, int nIter) {
    __shared__ int lcur[512];
    int blk = blockIdx.x, tid = threadIdx.x;
    for (int i = tid; i < NBUCK; i += 256)
        lcur[i] = bbase[i] + hist_g[(size_t)blk * NBUCK + i];
    __syncthreads();
    int base = blk * nIter * 256;
    for (int i = 0; i < nIter; ++i) {
        int e = base + i * 256 + tid;
        if (e >= Etot) continue;
        int s, d;
        if (e < E) { s = src[e]; d = dst[e]; } else { s = d = e - E; }
        int pos = atomicAdd(&lcur[d >> BSH], 1);
        bbuf[pos] = (unsigned)s | ((unsigned)(d & ((1 << BSH) - 1)) << 24);
    }
}

// Phase B: per bucket, build node-level CSR (offs + col) with LDS counting sort
__global__ __launch_bounds__(256) void bucket_build(const unsigned int* __restrict__ bbuf,
                                                    const int* __restrict__ bbase,
                                                    const int* __restrict__ tot,
                                                    int* __restrict__ col,
                                                    int* __restrict__ offs,
                                                    int N, int NBUCK) {
    __shared__ int cnt[256], lcur[256], s[256];
    __shared__ int ordered[CAPB];
    int b = blockIdx.x, tid = threadIdx.x;
    int bb = bbase[b];
    int t = tot[b];
    int n0 = b << BSH;
    cnt[tid] = 0;
    __syncthreads();
    for (int i = tid; i < t; i += 256) {
        unsigned v = bbuf[bb + i];
        atomicAdd(&cnt[v >> 24], 1);
    }
    __syncthreads();
    int c = cnt[tid];
    s[tid] = c; __syncthreads();
#pragma unroll
    for (int off = 1; off < 256; off <<= 1) {
        int tt = (tid >= off) ? s[tid - off] : 0;
        __syncthreads();
        s[tid] += tt;
        __syncthreads();
    }
    int ex = s[tid] - c;
    lcur[tid] = ex;
    if (n0 + tid < N) offs[n0 + tid] = bb + ex;
    __syncthreads();
    if (t <= CAPB) {
        for (int i = tid; i < t; i += 256) {
            unsigned v = bbuf[bb + i];
            int pos = atomicAdd(&lcur[v >> 24], 1);
            ordered[pos] = (int)(v & 0xFFFFFFu);
        }
        __syncthreads();
        for (int i = tid; i < t; i += 256) col[bb + i] = ordered[i];
    } else {  // fallback (never expected for near-uniform dst)
        for (int i = tid; i < t; i += 256) {
            unsigned v = bbuf[bb + i];
            int pos = atomicAdd(&lcur[v >> 24], 1);
            col[bb + pos] = (int)(v & 0xFFFFFFu);
        }
    }
}

// ---------------- fused gather: softmax (no-max form) + aggregate + epilogue ----------
// one wave per dst node; lane = (head<<4)|channel.
__global__ __launch_bounds__(256) void gat_gather(const int* __restrict__ offs,
                                                  const int* __restrict__ col,
                                                  const float* __restrict__ es,
                                                  const float* __restrict__ ed,
                                                  const float* __restrict__ h,
                                                  const float* __restrict__ b,
                                                  float* __restrict__ xo, int N) {
    int w = (blockIdx.x * 256 + threadIdx.x) >> 6;
    if (w >= N) return;
    int lane = threadIdx.x & 63, hd = lane >> 4;
    int beg = offs[w], cnt = offs[w + 1] - beg;
    float edv = ed[(size_t)w * 4 + hd];
    float l = 0.f, acc = 0.f;
    int j = 0;
    for (; j + 4 <= cnt; j += 4) {
        int s0 = col[beg + j + 0], s1 = col[beg + j + 1];
        int s2 = col[beg + j + 2], s3 = col[beg + j + 3];
        float a0 = lrelu(es[(size_t)s0 * 4 + hd] + edv);
        float a1 = lrelu(es[(size_t)s1 * 4 + hd] + edv);
        float a2 = lrelu(es[(size_t)s2 * 4 + hd] + edv);
        float a3 = lrelu(es[(size_t)s3 * 4 + hd] + edv);
        float h0 = h[(size_t)s0 * 64 + lane];
        float h1 = h[(size_t)s1 * 64 + lane];
        float h2 = h[(size_t)s2 * 64 + lane];
        float h3 = h[(size_t)s3 * 64 + lane];
        float p0 = expf(a0), p1 = expf(a1), p2 = expf(a2), p3 = expf(a3);
        l += (p0 + p1) + (p2 + p3);
        acc += p0 * h0 + p1 * h1 + p2 * h2 + p3 * h3;
    }
    for (; j < cnt; ++j) {
        int s = col[beg + j];
        float a = lrelu(es[(size_t)s * 4 + hd] + edv);
        float p = expf(a);
        l += p;
        acc += p * h[(size_t)s * 64 + lane];
    }
    float v = acc / (l + 1e-16f) + b[lane];
    xo[(size_t)w * 64 + lane] = v > 0.f ? v : expf(v) - 1.f;
}

// one wave per node: out[n] = dot(x2[n][:64], fcw) + fcb
__global__ void fc_out(const float* __restrict__ x2, const float* __restrict__ fcw,
                       const float* __restrict__ fcb, float* __restrict__ out, int N) {
    int g = blockIdx.x * 256 + threadIdx.x;
    int n = g >> 6;
    int lane = threadIdx.x & 63;
    if (n >= N) return;
    float v = x2[(size_t)n * 64 + lane] * fcw[lane];
#pragma unroll
    for (int off = 32; off > 0; off >>= 1) v += __shfl_down(v, off, 64);
    if (lane == 0) out[n] = v + fcb[0];
}

extern "C" void kernel_launch(void* const* d_in, const int* in_sizes, int n_in,
                              void* d_out, int out_size, void* d_ws, size_t ws_size,
                              hipStream_t stream) {
    const float* x   = (const float*)d_in[0];
    const int*   ei  = (const int*)d_in[1];
    const float* w1  = (const float*)d_in[2];
    const float* as1 = (const float*)d_in[3];
    const float* ad1 = (const float*)d_in[4];
    const float* b1  = (const float*)d_in[5];
    const float* w2  = (const float*)d_in[6];
    const float* as2 = (const float*)d_in[7];
    const float* ad2 = (const float*)d_in[8];
    const float* b2  = (const float*)d_in[9];
    const float* fcw = (const float*)d_in[10];
    const float* fcb = (const float*)d_in[11];
    float* out = (float*)d_out;

    const int N = in_sizes[0] / 128;  // 100000
    const int E = in_sizes[1] / 2;    // 1600000
    const int Etot = E + N;
    const int* src = ei;
    const int* dst = ei + E;

    const int NBUCK = (N + 255) >> BSH;          // 391 (<=512)
    int CHe = 8192;
    while ((Etot + CHe - 1) / CHe > 256) CHe *= 2;
    const int NBLK = (Etot + CHe - 1) / CHe;     // 208 (<=256)
    const int nIter = CHe / 256;

    char* p = (char*)d_ws;
    float* h     = (float*)p;  p += (size_t)N * 64 * 4;
    float* x2    = (float*)p;  p += (size_t)N * 64 * 4;
    float* es    = (float*)p;  p += (size_t)N * 4 * 4;
    float* ed    = (float*)p;  p += (size_t)N * 4 * 4;
    int* offs    = (int*)p;    p += (size_t)(N + 1) * 4;
    int* tot     = (int*)p;    p += (size_t)NBUCK * 4;
    int* bbase   = (int*)p;    p += (size_t)NBUCK * 4;
    int* hist_g  = (int*)p;    p += (size_t)NBLK * NBUCK * 4;
    int* col     = (int*)p;    p += (size_t)Etot * 4;
    unsigned int* bbuf = (unsigned int*)x2;      // alias: x2 unused until gather L1

    dim3 blk(256);
    const int gN64t = (N + 63) / 64;
    const int gNH  = (N * 4 + 255) / 256;
    const int gW   = (N * 64 + 255) / 256;

    // ---- CSR build (LDS bucket sort; shared by both layers) ----
    bucket_hist<<<NBLK, blk, 0, stream>>>(dst, hist_g, E, Etot, NBUCK, nIter);
    bucket_scan_blocks<<<NBUCK, blk, 0, stream>>>(hist_g, tot, NBUCK, NBLK);
    bucket_scan_tot<<<1, 512, 0, stream>>>(tot, bbase, offs, NBUCK, Etot, N);
    bucket_scatter<<<NBLK, blk, 0, stream>>>(src, dst, hist_g, bbase, bbuf, E, Etot, NBUCK, nIter);
    bucket_build<<<NBUCK, blk, 0, stream>>>(bbuf, bbase, tot, col, offs, N, NBUCK);

    // ---- layer 1 ----
    gemm_tile<128><<<gN64t, blk, 0, stream>>>(x, w1, h, N);
    attn_coef<<<gNH, blk, 0, stream>>>(h, as1, ad1, es, ed, N);
    gat_gather<<<gW, blk, 0, stream>>>(offs, col, es, ed, h, b1, x2, N);

    // ---- layer 2 ----
    gemm_tile<64><<<gN64t, blk, 0, stream>>>(x2, w2, h, N);
    attn_coef<<<gNH, blk, 0, stream>>>(h, as2, ad2, es, ed, N);
    gat_gather<<<gW, blk, 0, stream>>>(offs, col, es, ed, h, b2, x2, N);

    // ---- final FC ----
    fc_out<<<gW, blk, 0, stream>>>(x2, fcw, fcb, out, N);
}

// Round 5
// 291.490 us; speedup vs baseline: 46.0919x; 1.0231x over previous
//
#include <hip/hip_runtime.h>
#include <math.h>

#define NEG_SLOPE 0.2f
#define BSH 8              // 256 nodes per bucket
#define CAPB 6144          // phase-B LDS capacity (entries); mean ~4352

__device__ __forceinline__ float lrelu(float x) { return x > 0.f ? x : NEG_SLOPE * x; }

// ---------------- dense h = x @ W^T ----------------
// 64x64 tile per block, 4x4 per thread, k-major LDS staging.
template <int K>
__global__ __launch_bounds__(256) void gemm_tile(const float* __restrict__ x,
                                                 const float* __restrict__ W,
                                                 float* __restrict__ h, int N) {
    constexpr int CK = 32;
    __shared__ float xs[CK][68];
    __shared__ float ws[CK][68];
    const int tid = threadIdx.x;
    const int n0 = blockIdx.x * 64;
    const int tx = tid & 15, ty = tid >> 4;

    float acc[4][4] = {};

    for (int k0 = 0; k0 < K; k0 += CK) {
#pragma unroll
        for (int i = 0; i < 2; ++i) {
            int slot = tid + i * 256;
            int nl = slot >> 3;
            int kq = slot & 7;
            int n = n0 + nl;
            float4 v = (n < N) ? *(const float4*)(x + (size_t)n * K + k0 + kq * 4)
                               : make_float4(0.f, 0.f, 0.f, 0.f);
            xs[kq * 4 + 0][nl] = v.x; xs[kq * 4 + 1][nl] = v.y;
            xs[kq * 4 + 2][nl] = v.z; xs[kq * 4 + 3][nl] = v.w;
            float4 wv = *(const float4*)(W + (size_t)nl * K + k0 + kq * 4);
            ws[kq * 4 + 0][nl] = wv.x; ws[kq * 4 + 1][nl] = wv.y;
            ws[kq * 4 + 2][nl] = wv.z; ws[kq * 4 + 3][nl] = wv.w;
        }
        __syncthreads();
#pragma unroll
        for (int k = 0; k < CK; ++k) {
            float4 xv = *(const float4*)(&xs[k][ty * 4]);
            float4 wv = *(const float4*)(&ws[k][tx * 4]);
            float xa[4] = {xv.x, xv.y, xv.z, xv.w};
            float wa[4] = {wv.x, wv.y, wv.z, wv.w};
#pragma unroll
            for (int a = 0; a < 4; ++a)
#pragma unroll
                for (int c = 0; c < 4; ++c)
                    acc[a][c] += xa[a] * wa[c];
        }
        __syncthreads();
    }
#pragma unroll
    for (int a = 0; a < 4; ++a) {
        int n = n0 + ty * 4 + a;
        if (n < N)
            *(float4*)(h + (size_t)n * 64 + tx * 4) =
                make_float4(acc[a][0], acc[a][1], acc[a][2], acc[a][3]);
    }
}

// per (node, head): e_src/e_dst dot products over 16 channels
__global__ void attn_coef(const float* __restrict__ h, const float* __restrict__ a_src,
                          const float* __restrict__ a_dst, float* __restrict__ e_src,
                          float* __restrict__ e_dst, int N) {
    int t = blockIdx.x * 256 + threadIdx.x;
    if (t >= N * 4) return;
    int n = t >> 2, hd = t & 3;
    const float4* hp = (const float4*)(h + (size_t)n * 64 + hd * 16);
    const float4* as = (const float4*)(a_src + hd * 16);
    const float4* ad = (const float4*)(a_dst + hd * 16);
    float es = 0.f, ed = 0.f;
#pragma unroll
    for (int q = 0; q < 4; ++q) {
        float4 hv = hp[q], av = as[q], dv = ad[q];
        es += hv.x * av.x + hv.y * av.y + hv.z * av.z + hv.w * av.w;
        ed += hv.x * dv.x + hv.y * dv.y + hv.z * dv.z + hv.w * dv.w;
    }
    e_src[t] = es;
    e_dst[t] = ed;
}

// ---------------- CSR build: LDS bucket sort (no global atomics) ----------------
__global__ __launch_bounds__(256) void bucket_hist(const int* __restrict__ dst,
                                                   int* __restrict__ hist_g,
                                                   int E, int Etot, int NBUCK, int nIter) {
    __shared__ int hist[512];
    int blk = blockIdx.x, tid = threadIdx.x;
    for (int i = tid; i < NBUCK; i += 256) hist[i] = 0;
    __syncthreads();
    int base = blk * nIter * 256;
    for (int i = 0; i < nIter; ++i) {
        int e = base + i * 256 + tid;
        if (e < Etot) {
            int d = (e < E) ? dst[e] : e - E;
            atomicAdd(&hist[d >> BSH], 1);
        }
    }
    __syncthreads();
    for (int i = tid; i < NBUCK; i += 256) hist_g[(size_t)blk * NBUCK + i] = hist[i];
}

__global__ __launch_bounds__(256) void bucket_scan_blocks(int* __restrict__ hist_g,
                                                          int* __restrict__ tot,
                                                          int NBUCK, int NBLK) {
    __shared__ int s[256];
    int b = blockIdx.x, tid = threadIdx.x;
    int v = (tid < NBLK) ? hist_g[(size_t)tid * NBUCK + b] : 0;
    s[tid] = v; __syncthreads();
#pragma unroll
    for (int off = 1; off < 256; off <<= 1) {
        int t = (tid >= off) ? s[tid - off] : 0;
        __syncthreads();
        s[tid] += t;
        __syncthreads();
    }
    if (tid < NBLK) hist_g[(size_t)tid * NBUCK + b] = s[tid] - v;  // exclusive
    if (tid == 255) tot[b] = s[255];
}

__global__ void bucket_scan_tot(const int* __restrict__ tot, int* __restrict__ bbase,
                                int* __restrict__ offs, int NBUCK, int Etot, int N) {
    __shared__ int s[512];
    int tid = threadIdx.x;
    int v = (tid < NBUCK) ? tot[tid] : 0;
    s[tid] = v; __syncthreads();
#pragma unroll
    for (int off = 1; off < 512; off <<= 1) {
        int t = (tid >= off) ? s[tid - off] : 0;
        __syncthreads();
        s[tid] += t;
        __syncthreads();
    }
    if (tid < NBUCK) bbase[tid] = s[tid] - v;
    if (tid == 0) offs[N] = Etot;
}

__global__ __launch_bounds__(256) void bucket_scatter(const int* __restrict__ src,
                                                      const int* __restrict__ dst,
                                                      const int* __restrict__ hist_g,
                                                      const int* __restrict__ bbase,
                                                      unsigned int* __restrict__ bbuf,
                                                      int E, int Etot, int NBUCK, int nIter) {
    __shared__ int lcur[512];
    int blk = blockIdx.x, tid = threadIdx.x;
    for (int i = tid; i < NBUCK; i += 256)
        lcur[i] = bbase[i] + hist_g[(size_t)blk * NBUCK + i];
    __syncthreads();
    int base = blk * nIter * 256;
    for (int i = 0; i < nIter; ++i) {
        int e = base + i * 256 + tid;
        if (e >= Etot) continue;
        int s, d;
        if (e < E) { s = src[e]; d = dst[e]; } else { s = d = e - E; }
        int pos = atomicAdd(&lcur[d >> BSH], 1);
        bbuf[pos] = (unsigned)s | ((unsigned)(d & ((1 << BSH) - 1)) << 24);
    }
}

__global__ __launch_bounds__(256) void bucket_build(const unsigned int* __restrict__ bbuf,
                                                    const int* __restrict__ bbase,
                                                    const int* __restrict__ tot,
                                                    int* __restrict__ col,
                                                    int* __restrict__ offs,
                                                    int N, int NBUCK) {
    __shared__ int cnt[256], lcur[256], s[256];
    __shared__ int ordered[CAPB];
    int b = blockIdx.x, tid = threadIdx.x;
    int bb = bbase[b];
    int t = tot[b];
    int n0 = b << BSH;
    cnt[tid] = 0;
    __syncthreads();
    for (int i = tid; i < t; i += 256) {
        unsigned v = bbuf[bb + i];
        atomicAdd(&cnt[v >> 24], 1);
    }
    __syncthreads();
    int c = cnt[tid];
    s[tid] = c; __syncthreads();
#pragma unroll
    for (int off = 1; off < 256; off <<= 1) {
        int tt = (tid >= off) ? s[tid - off] : 0;
        __syncthreads();
        s[tid] += tt;
        __syncthreads();
    }
    int ex = s[tid] - c;
    lcur[tid] = ex;
    if (n0 + tid < N) offs[n0 + tid] = bb + ex;
    __syncthreads();
    if (t <= CAPB) {
        for (int i = tid; i < t; i += 256) {
            unsigned v = bbuf[bb + i];
            int pos = atomicAdd(&lcur[v >> 24], 1);
            ordered[pos] = (int)(v & 0xFFFFFFu);
        }
        __syncthreads();
        for (int i = tid; i < t; i += 256) col[bb + i] = ordered[i];
    } else {  // fallback (never expected for near-uniform dst)
        for (int i = tid; i < t; i += 256) {
            unsigned v = bbuf[bb + i];
            int pos = atomicAdd(&lcur[v >> 24], 1);
            col[bb + pos] = (int)(v & 0xFFFFFFu);
        }
    }
}

// ---------------- fused gather: 4 edges/wave, float4/lane ----------------
// lane = (eslot<<4) | cq ; eslot in [0,4) handles edge j+eslot; cq in [0,16)
// handles channels [4cq,4cq+4); head = cq>>2. Softmax in no-max form (logits
// bounded), epilogue: /denom + bias + ELU; FINAL fuses the fc dot product.
template <bool FINAL>
__global__ __launch_bounds__(256) void gat_gather4(const int* __restrict__ offs,
                                                   const int* __restrict__ col,
                                                   const float* __restrict__ es,
                                                   const float* __restrict__ ed,
                                                   const float* __restrict__ h,
                                                   const float* __restrict__ b,
                                                   const float* __restrict__ fcw,
                                                   const float* __restrict__ fcb,
                                                   float* __restrict__ xo, int N) {
    int w = (blockIdx.x * 256 + threadIdx.x) >> 6;
    if (w >= N) return;
    const int lane = threadIdx.x & 63;
    const int eslot = lane >> 4, cq = lane & 15, hd = cq >> 2;
    const int beg = offs[w];
    const int cnt = offs[w + 1] - beg;
    const float edv = ed[(size_t)w * 4 + hd];

    float4 acc = make_float4(0.f, 0.f, 0.f, 0.f);
    float l = 0.f;
    for (int j = 0; j < cnt; j += 4) {
        int k = j + eslot;
        bool valid = k < cnt;
        int s = valid ? col[beg + k] : 0;
        float a = es[(size_t)s * 4 + hd] + edv;
        a = a > 0.f ? a : NEG_SLOPE * a;
        float p = valid ? __expf(a) : 0.f;
        float4 hv = *(const float4*)(h + (size_t)s * 64 + cq * 4);
        acc.x += p * hv.x; acc.y += p * hv.y;
        acc.z += p * hv.z; acc.w += p * hv.w;
        l += p;
    }
    // reduce across the 4 eslots (lanes l, l^16, l^32, l^48)
#pragma unroll
    for (int m = 16; m <= 32; m <<= 1) {
        acc.x += __shfl_xor(acc.x, m, 64);
        acc.y += __shfl_xor(acc.y, m, 64);
        acc.z += __shfl_xor(acc.z, m, 64);
        acc.w += __shfl_xor(acc.w, m, 64);
        l     += __shfl_xor(l, m, 64);
    }
    const float inv = 1.f / (l + 1e-16f);
    const float4 bv = *(const float4*)(b + cq * 4);
    float4 v;
    v.x = acc.x * inv + bv.x;
    v.y = acc.y * inv + bv.y;
    v.z = acc.z * inv + bv.z;
    v.w = acc.w * inv + bv.w;
    v.x = v.x > 0.f ? v.x : __expf(v.x) - 1.f;
    v.y = v.y > 0.f ? v.y : __expf(v.y) - 1.f;
    v.z = v.z > 0.f ? v.z : __expf(v.z) - 1.f;
    v.w = v.w > 0.f ? v.w : __expf(v.w) - 1.f;
    if (FINAL) {
        const float4 fw = *(const float4*)(fcw + cq * 4);
        float t = v.x * fw.x + v.y * fw.y + v.z * fw.z + v.w * fw.w;
#pragma unroll
        for (int m = 1; m <= 8; m <<= 1) t += __shfl_xor(t, m, 64);
        if (lane == 0) xo[w] = t + fcb[0];
    } else {
        if (lane < 16)
            *(float4*)(xo + (size_t)w * 64 + cq * 4) = v;
    }
}

extern "C" void kernel_launch(void* const* d_in, const int* in_sizes, int n_in,
                              void* d_out, int out_size, void* d_ws, size_t ws_size,
                              hipStream_t stream) {
    const float* x   = (const float*)d_in[0];
    const int*   ei  = (const int*)d_in[1];
    const float* w1  = (const float*)d_in[2];
    const float* as1 = (const float*)d_in[3];
    const float* ad1 = (const float*)d_in[4];
    const float* b1  = (const float*)d_in[5];
    const float* w2  = (const float*)d_in[6];
    const float* as2 = (const float*)d_in[7];
    const float* ad2 = (const float*)d_in[8];
    const float* b2  = (const float*)d_in[9];
    const float* fcw = (const float*)d_in[10];
    const float* fcb = (const float*)d_in[11];
    float* out = (float*)d_out;

    const int N = in_sizes[0] / 128;  // 100000
    const int E = in_sizes[1] / 2;    // 1600000
    const int Etot = E + N;
    const int* src = ei;
    const int* dst = ei + E;

    const int NBUCK = (N + 255) >> BSH;          // 391 (<=512)
    int CHe = 8192;
    while ((Etot + CHe - 1) / CHe > 256) CHe *= 2;
    const int NBLK = (Etot + CHe - 1) / CHe;     // 208 (<=256)
    const int nIter = CHe / 256;

    char* p = (char*)d_ws;
    float* h     = (float*)p;  p += (size_t)N * 64 * 4;
    float* x2    = (float*)p;  p += (size_t)N * 64 * 4;
    float* es    = (float*)p;  p += (size_t)N * 4 * 4;
    float* ed    = (float*)p;  p += (size_t)N * 4 * 4;
    int* offs    = (int*)p;    p += (size_t)(N + 1) * 4;
    int* tot     = (int*)p;    p += (size_t)NBUCK * 4;
    int* bbase   = (int*)p;    p += (size_t)NBUCK * 4;
    int* hist_g  = (int*)p;    p += (size_t)NBLK * NBUCK * 4;
    int* col     = (int*)p;    p += (size_t)Etot * 4;
    unsigned int* bbuf = (unsigned int*)x2;      // alias: x2 unused until gather L1

    dim3 blk(256);
    const int gN64t = (N + 63) / 64;
    const int gNH  = (N * 4 + 255) / 256;
    const int gW   = (N * 64 + 255) / 256;

    // ---- CSR build (LDS bucket sort; shared by both layers) ----
    bucket_hist<<<NBLK, blk, 0, stream>>>(dst, hist_g, E, Etot, NBUCK, nIter);
    bucket_scan_blocks<<<NBUCK, blk, 0, stream>>>(hist_g, tot, NBUCK, NBLK);
    bucket_scan_tot<<<1, 512, 0, stream>>>(tot, bbase, offs, NBUCK, Etot, N);
    bucket_scatter<<<NBLK, blk, 0, stream>>>(src, dst, hist_g, bbase, bbuf, E, Etot, NBUCK, nIter);
    bucket_build<<<NBUCK, blk, 0, stream>>>(bbuf, bbase, tot, col, offs, N, NBUCK);

    // ---- layer 1 ----
    gemm_tile<128><<<gN64t, blk, 0, stream>>>(x, w1, h, N);
    attn_coef<<<gNH, blk, 0, stream>>>(h, as1, ad1, es, ed, N);
    gat_gather4<false><<<gW, blk, 0, stream>>>(offs, col, es, ed, h, b1, nullptr, nullptr, x2, N);

    // ---- layer 2 ----
    gemm_tile<64><<<gN64t, blk, 0, stream>>>(x2, w2, h, N);
    attn_coef<<<gNH, blk, 0, stream>>>(h, as2, ad2, es, ed, N);
    gat_gather4<true><<<gW, blk, 0, stream>>>(offs, col, es, ed, h, b2, fcw, fcb, out, N);
}

// Round 6
// 271.111 us; speedup vs baseline: 49.5566x; 1.0752x over previous
//
#include <hip/hip_runtime.h>
#include <math.h>

#define NEG_SLOPE 0.2f
#define BSH 8              // 256 nodes per bucket
#define CAPB 6144          // phase-B LDS capacity (entries); mean ~4352

__device__ __forceinline__ unsigned bf16_rne(float x) {
    unsigned u = __float_as_uint(x);
    return (u + 0x7FFFu + ((u >> 16) & 1u)) >> 16;
}

// ---------------- dense h = x @ W^T, fused attn coefs, bf16 h output -----------
// 64x64 tile per block, 4x4 per thread, k-major LDS staging.
// Outputs: h_bf[n][64] bf16; es/ed[n][4] fp32 (dot of h row with a_src/a_dst).
template <int K>
__global__ __launch_bounds__(256) void gemm_tile(const float* __restrict__ x,
                                                 const float* __restrict__ W,
                                                 const float* __restrict__ a_src,
                                                 const float* __restrict__ a_dst,
                                                 unsigned short* __restrict__ h_bf,
                                                 float* __restrict__ es,
                                                 float* __restrict__ ed,
                                                 int N) {
    constexpr int CK = 32;
    __shared__ float xs[CK][68];
    __shared__ float ws[CK][68];
    const int tid = threadIdx.x;
    const int n0 = blockIdx.x * 64;
    const int tx = tid & 15, ty = tid >> 4;

    float acc[4][4] = {};

    for (int k0 = 0; k0 < K; k0 += CK) {
#pragma unroll
        for (int i = 0; i < 2; ++i) {
            int slot = tid + i * 256;
            int nl = slot >> 3;
            int kq = slot & 7;
            int n = n0 + nl;
            float4 v = (n < N) ? *(const float4*)(x + (size_t)n * K + k0 + kq * 4)
                               : make_float4(0.f, 0.f, 0.f, 0.f);
            xs[kq * 4 + 0][nl] = v.x; xs[kq * 4 + 1][nl] = v.y;
            xs[kq * 4 + 2][nl] = v.z; xs[kq * 4 + 3][nl] = v.w;
            float4 wv = *(const float4*)(W + (size_t)nl * K + k0 + kq * 4);
            ws[kq * 4 + 0][nl] = wv.x; ws[kq * 4 + 1][nl] = wv.y;
            ws[kq * 4 + 2][nl] = wv.z; ws[kq * 4 + 3][nl] = wv.w;
        }
        __syncthreads();
#pragma unroll
        for (int k = 0; k < CK; ++k) {
            float4 xv = *(const float4*)(&xs[k][ty * 4]);
            float4 wv = *(const float4*)(&ws[k][tx * 4]);
            float xa[4] = {xv.x, xv.y, xv.z, xv.w};
            float wa[4] = {wv.x, wv.y, wv.z, wv.w};
#pragma unroll
            for (int a = 0; a < 4; ++a)
#pragma unroll
                for (int c = 0; c < 4; ++c)
                    acc[a][c] += xa[a] * wa[c];
        }
        __syncthreads();
    }

    // a_src/a_dst flat layout [head*16+ch] == h column index; this thread owns cols tx*4..+3
    const float4 av = *(const float4*)(a_src + tx * 4);
    const float4 dv = *(const float4*)(a_dst + tx * 4);
#pragma unroll
    for (int a = 0; a < 4; ++a) {
        int n = n0 + ty * 4 + a;
        // bf16 pack (2x uint = 4 bf16)
        uint2 pk;
        pk.x = bf16_rne(acc[a][0]) | (bf16_rne(acc[a][1]) << 16);
        pk.y = bf16_rne(acc[a][2]) | (bf16_rne(acc[a][3]) << 16);
        if (n < N)
            *(uint2*)(h_bf + (size_t)n * 64 + tx * 4) = pk;
        // attention coefs: reduce dot over the 4 threads of this head group
        float e1 = acc[a][0] * av.x + acc[a][1] * av.y + acc[a][2] * av.z + acc[a][3] * av.w;
        float e2 = acc[a][0] * dv.x + acc[a][1] * dv.y + acc[a][2] * dv.z + acc[a][3] * dv.w;
        e1 += __shfl_xor(e1, 1, 64); e2 += __shfl_xor(e2, 1, 64);
        e1 += __shfl_xor(e1, 2, 64); e2 += __shfl_xor(e2, 2, 64);
        if ((tx & 3) == 0 && n < N) {
            es[(size_t)n * 4 + (tx >> 2)] = e1;
            ed[(size_t)n * 4 + (tx >> 2)] = e2;
        }
    }
}

// ---------------- CSR build: LDS bucket sort (no global atomics) ----------------
__global__ __launch_bounds__(256) void bucket_hist(const int* __restrict__ dst,
                                                   int* __restrict__ hist_g,
                                                   int E, int Etot, int NBUCK, int nIter) {
    __shared__ int hist[512];
    int blk = blockIdx.x, tid = threadIdx.x;
    for (int i = tid; i < NBUCK; i += 256) hist[i] = 0;
    __syncthreads();
    int base = blk * nIter * 256;
    for (int i = 0; i < nIter; ++i) {
        int e = base + i * 256 + tid;
        if (e < Etot) {
            int d = (e < E) ? dst[e] : e - E;
            atomicAdd(&hist[d >> BSH], 1);
        }
    }
    __syncthreads();
    for (int i = tid; i < NBUCK; i += 256) hist_g[(size_t)blk * NBUCK + i] = hist[i];
}

__global__ __launch_bounds__(256) void bucket_scan_blocks(int* __restrict__ hist_g,
                                                          int* __restrict__ tot,
                                                          int NBUCK, int NBLK) {
    __shared__ int s[256];
    int b = blockIdx.x, tid = threadIdx.x;
    int v = (tid < NBLK) ? hist_g[(size_t)tid * NBUCK + b] : 0;
    s[tid] = v; __syncthreads();
#pragma unroll
    for (int off = 1; off < 256; off <<= 1) {
        int t = (tid >= off) ? s[tid - off] : 0;
        __syncthreads();
        s[tid] += t;
        __syncthreads();
    }
    if (tid < NBLK) hist_g[(size_t)tid * NBUCK + b] = s[tid] - v;  // exclusive
    if (tid == 255) tot[b] = s[255];
}

__global__ void bucket_scan_tot(const int* __restrict__ tot, int* __restrict__ bbase,
                                int* __restrict__ offs, int NBUCK, int Etot, int N) {
    __shared__ int s[512];
    int tid = threadIdx.x;
    int v = (tid < NBUCK) ? tot[tid] : 0;
    s[tid] = v; __syncthreads();
#pragma unroll
    for (int off = 1; off < 512; off <<= 1) {
        int t = (tid >= off) ? s[tid - off] : 0;
        __syncthreads();
        s[tid] += t;
        __syncthreads();
    }
    if (tid < NBUCK) bbase[tid] = s[tid] - v;
    if (tid == 0) offs[N] = Etot;
}

__global__ __launch_bounds__(256) void bucket_scatter(const int* __restrict__ src,
                                                      const int* __restrict__ dst,
                                                      const int* __restrict__ hist_g,
                                                      const int* __restrict__ bbase,
                                                      unsigned int* __restrict__ bbuf,
                                                      int E, int Etot, int NBUCK, int nIter) {
    __shared__ int lcur[512];
    int blk = blockIdx.x, tid = threadIdx.x;
    for (int i = tid; i < NBUCK; i += 256)
        lcur[i] = bbase[i] + hist_g[(size_t)blk * NBUCK + i];
    __syncthreads();
    int base = blk * nIter * 256;
    for (int i = 0; i < nIter; ++i) {
        int e = base + i * 256 + tid;
        if (e >= Etot) continue;
        int s, d;
        if (e < E) { s = src[e]; d = dst[e]; } else { s = d = e - E; }
        int pos = atomicAdd(&lcur[d >> BSH], 1);
        bbuf[pos] = (unsigned)s | ((unsigned)(d & ((1 << BSH) - 1)) << 24);
    }
}

__global__ __launch_bounds__(256) void bucket_build(const unsigned int* __restrict__ bbuf,
                                                    const int* __restrict__ bbase,
                                                    const int* __restrict__ tot,
                                                    int* __restrict__ col,
                                                    int* __restrict__ offs,
                                                    int N, int NBUCK) {
    __shared__ int cnt[256], lcur[256], s[256];
    __shared__ int ordered[CAPB];
    int b = blockIdx.x, tid = threadIdx.x;
    int bb = bbase[b];
    int t = tot[b];
    int n0 = b << BSH;
    cnt[tid] = 0;
    __syncthreads();
    for (int i = tid; i < t; i += 256) {
        unsigned v = bbuf[bb + i];
        atomicAdd(&cnt[v >> 24], 1);
    }
    __syncthreads();
    int c = cnt[tid];
    s[tid] = c; __syncthreads();
#pragma unroll
    for (int off = 1; off < 256; off <<= 1) {
        int tt = (tid >= off) ? s[tid - off] : 0;
        __syncthreads();
        s[tid] += tt;
        __syncthreads();
    }
    int ex = s[tid] - c;
    lcur[tid] = ex;
    if (n0 + tid < N) offs[n0 + tid] = bb + ex;
    __syncthreads();
    if (t <= CAPB) {
        for (int i = tid; i < t; i += 256) {
            unsigned v = bbuf[bb + i];
            int pos = atomicAdd(&lcur[v >> 24], 1);
            ordered[pos] = (int)(v & 0xFFFFFFu);
        }
        __syncthreads();
        for (int i = tid; i < t; i += 256) col[bb + i] = ordered[i];
    } else {  // fallback (never expected for near-uniform dst)
        for (int i = tid; i < t; i += 256) {
            unsigned v = bbuf[bb + i];
            int pos = atomicAdd(&lcur[v >> 24], 1);
            col[bb + pos] = (int)(v & 0xFFFFFFu);
        }
    }
}

// ---------------- fused gather: 4 edges/wave, bf16 h (8B/lane) ----------------
// lane = (eslot<<4) | cq ; eslot in [0,4) handles edge j+eslot; cq in [0,16)
// handles channels [4cq,4cq+4); head = cq>>2. Softmax in no-max form (logits
// bounded); epilogue: /denom + bias + ELU; FINAL fuses the fc dot product.
template <bool FINAL>
__global__ __launch_bounds__(256) void gat_gather4(const int* __restrict__ offs,
                                                   const int* __restrict__ col,
                                                   const float* __restrict__ es,
                                                   const float* __restrict__ ed,
                                                   const unsigned short* __restrict__ h_bf,
                                                   const float* __restrict__ b,
                                                   const float* __restrict__ fcw,
                                                   const float* __restrict__ fcb,
                                                   float* __restrict__ xo, int N) {
    int w = (blockIdx.x * 256 + threadIdx.x) >> 6;
    if (w >= N) return;
    const int lane = threadIdx.x & 63;
    const int eslot = lane >> 4, cq = lane & 15, hd = cq >> 2;
    const int beg = offs[w];
    const int cnt = offs[w + 1] - beg;
    const float edv = ed[(size_t)w * 4 + hd];

    float4 acc = make_float4(0.f, 0.f, 0.f, 0.f);
    float l = 0.f;
    for (int j = 0; j < cnt; j += 4) {
        int k = j + eslot;
        bool valid = k < cnt;
        int s = valid ? col[beg + k] : 0;
        float a = es[(size_t)s * 4 + hd] + edv;
        a = a > 0.f ? a : NEG_SLOPE * a;
        float p = valid ? __expf(a) : 0.f;
        uint2 hv = *(const uint2*)(h_bf + (size_t)s * 64 + cq * 4);
        float h0 = __uint_as_float(hv.x << 16);
        float h1 = __uint_as_float(hv.x & 0xFFFF0000u);
        float h2 = __uint_as_float(hv.y << 16);
        float h3 = __uint_as_float(hv.y & 0xFFFF0000u);
        acc.x += p * h0; acc.y += p * h1;
        acc.z += p * h2; acc.w += p * h3;
        l += p;
    }
    // reduce across the 4 eslots (lanes l, l^16, l^32, l^48)
#pragma unroll
    for (int m = 16; m <= 32; m <<= 1) {
        acc.x += __shfl_xor(acc.x, m, 64);
        acc.y += __shfl_xor(acc.y, m, 64);
        acc.z += __shfl_xor(acc.z, m, 64);
        acc.w += __shfl_xor(acc.w, m, 64);
        l     += __shfl_xor(l, m, 64);
    }
    const float inv = 1.f / (l + 1e-16f);
    const float4 bv = *(const float4*)(b + cq * 4);
    float4 v;
    v.x = acc.x * inv + bv.x;
    v.y = acc.y * inv + bv.y;
    v.z = acc.z * inv + bv.z;
    v.w = acc.w * inv + bv.w;
    v.x = v.x > 0.f ? v.x : __expf(v.x) - 1.f;
    v.y = v.y > 0.f ? v.y : __expf(v.y) - 1.f;
    v.z = v.z > 0.f ? v.z : __expf(v.z) - 1.f;
    v.w = v.w > 0.f ? v.w : __expf(v.w) - 1.f;
    if (FINAL) {
        const float4 fw = *(const float4*)(fcw + cq * 4);
        float t = v.x * fw.x + v.y * fw.y + v.z * fw.z + v.w * fw.w;
#pragma unroll
        for (int m = 1; m <= 8; m <<= 1) t += __shfl_xor(t, m, 64);
        if (lane == 0) xo[w] = t + fcb[0];
    } else {
        if (lane < 16)
            *(float4*)(xo + (size_t)w * 64 + cq * 4) = v;
    }
}

extern "C" void kernel_launch(void* const* d_in, const int* in_sizes, int n_in,
                              void* d_out, int out_size, void* d_ws, size_t ws_size,
                              hipStream_t stream) {
    const float* x   = (const float*)d_in[0];
    const int*   ei  = (const int*)d_in[1];
    const float* w1  = (const float*)d_in[2];
    const float* as1 = (const float*)d_in[3];
    const float* ad1 = (const float*)d_in[4];
    const float* b1  = (const float*)d_in[5];
    const float* w2  = (const float*)d_in[6];
    const float* as2 = (const float*)d_in[7];
    const float* ad2 = (const float*)d_in[8];
    const float* b2  = (const float*)d_in[9];
    const float* fcw = (const float*)d_in[10];
    const float* fcb = (const float*)d_in[11];
    float* out = (float*)d_out;

    const int N = in_sizes[0] / 128;  // 100000
    const int E = in_sizes[1] / 2;    // 1600000
    const int Etot = E + N;
    const int* src = ei;
    const int* dst = ei + E;

    const int NBUCK = (N + 255) >> BSH;          // 391 (<=512)
    int CHe = 8192;
    while ((Etot + CHe - 1) / CHe > 256) CHe *= 2;
    const int NBLK = (Etot + CHe - 1) / CHe;     // 208 (<=256)
    const int nIter = CHe / 256;

    char* p = (char*)d_ws;
    unsigned short* h_bf = (unsigned short*)p;  p += (size_t)N * 64 * 2;
    float* x2    = (float*)p;  p += (size_t)N * 64 * 4;
    float* es    = (float*)p;  p += (size_t)N * 4 * 4;
    float* ed    = (float*)p;  p += (size_t)N * 4 * 4;
    int* offs    = (int*)p;    p += (size_t)(N + 1) * 4;
    int* tot     = (int*)p;    p += (size_t)NBUCK * 4;
    int* bbase   = (int*)p;    p += (size_t)NBUCK * 4;
    int* hist_g  = (int*)p;    p += (size_t)NBLK * NBUCK * 4;
    int* col     = (int*)p;    p += (size_t)Etot * 4;
    unsigned int* bbuf = (unsigned int*)x2;      // alias: x2 unused until gather L1

    dim3 blk(256);
    const int gN64t = (N + 63) / 64;
    const int gW   = (N * 64 + 255) / 256;

    // ---- CSR build (LDS bucket sort; shared by both layers) ----
    bucket_hist<<<NBLK, blk, 0, stream>>>(dst, hist_g, E, Etot, NBUCK, nIter);
    bucket_scan_blocks<<<NBUCK, blk, 0, stream>>>(hist_g, tot, NBUCK, NBLK);
    bucket_scan_tot<<<1, 512, 0, stream>>>(tot, bbase, offs, NBUCK, Etot, N);
    bucket_scatter<<<NBLK, blk, 0, stream>>>(src, dst, hist_g, bbase, bbuf, E, Etot, NBUCK, nIter);
    bucket_build<<<NBUCK, blk, 0, stream>>>(bbuf, bbase, tot, col, offs, N, NBUCK);

    // ---- layer 1 ----
    gemm_tile<128><<<gN64t, blk, 0, stream>>>(x, w1, as1, ad1, h_bf, es, ed, N);
    gat_gather4<false><<<gW, blk, 0, stream>>>(offs, col, es, ed, h_bf, b1, nullptr, nullptr, x2, N);

    // ---- layer 2 ----
    gemm_tile<64><<<gN64t, blk, 0, stream>>>(x2, w2, as2, ad2, h_bf, es, ed, N);
    gat_gather4<true><<<gW, blk, 0, stream>>>(offs, col, es, ed, h_bf, b2, fcw, fcb, out, N);
}

// Round 7
// 225.197 us; speedup vs baseline: 59.6603x; 1.2039x over previous
//
#include <hip/hip_runtime.h>
#include <math.h>

#define NEG_SLOPE 0.2f
#define BSH 8              // 256 nodes per bucket
#define CAPB 6144          // phase-B LDS capacity (entries); mean ~4352

__device__ __forceinline__ unsigned bf16_rne(float x) {
    unsigned u = __float_as_uint(x);
    return (u + 0x7FFFu + ((u >> 16) & 1u)) >> 16;
}
__device__ __forceinline__ float bf_lo(unsigned u) { return __uint_as_float(u << 16); }
__device__ __forceinline__ float bf_hi(unsigned u) { return __uint_as_float(u & 0xFFFF0000u); }

// ---------------- dense h = x @ W^T, fused attn coefs, bf16 h output -----------
// 64x64 tile per block, 4x4 per thread, k-major LDS staging.
// Outputs: h_bf[n][64] bf16; es/ed[n][4] fp32 (dot of h row with a_src/a_dst).
template <int K>
__global__ __launch_bounds__(256) void gemm_tile(const float* __restrict__ x,
                                                 const float* __restrict__ W,
                                                 const float* __restrict__ a_src,
                                                 const float* __restrict__ a_dst,
                                                 unsigned short* __restrict__ h_bf,
                                                 float* __restrict__ es,
                                                 float* __restrict__ ed,
                                                 int N) {
    constexpr int CK = 32;
    __shared__ float xs[CK][68];
    __shared__ float ws[CK][68];
    const int tid = threadIdx.x;
    const int n0 = blockIdx.x * 64;
    const int tx = tid & 15, ty = tid >> 4;

    float acc[4][4] = {};

    for (int k0 = 0; k0 < K; k0 += CK) {
#pragma unroll
        for (int i = 0; i < 2; ++i) {
            int slot = tid + i * 256;
            int nl = slot >> 3;
            int kq = slot & 7;
            int n = n0 + nl;
            float4 v = (n < N) ? *(const float4*)(x + (size_t)n * K + k0 + kq * 4)
                               : make_float4(0.f, 0.f, 0.f, 0.f);
            xs[kq * 4 + 0][nl] = v.x; xs[kq * 4 + 1][nl] = v.y;
            xs[kq * 4 + 2][nl] = v.z; xs[kq * 4 + 3][nl] = v.w;
            float4 wv = *(const float4*)(W + (size_t)nl * K + k0 + kq * 4);
            ws[kq * 4 + 0][nl] = wv.x; ws[kq * 4 + 1][nl] = wv.y;
            ws[kq * 4 + 2][nl] = wv.z; ws[kq * 4 + 3][nl] = wv.w;
        }
        __syncthreads();
#pragma unroll
        for (int k = 0; k < CK; ++k) {
            float4 xv = *(const float4*)(&xs[k][ty * 4]);
            float4 wv = *(const float4*)(&ws[k][tx * 4]);
            float xa[4] = {xv.x, xv.y, xv.z, xv.w};
            float wa[4] = {wv.x, wv.y, wv.z, wv.w};
#pragma unroll
            for (int a = 0; a < 4; ++a)
#pragma unroll
                for (int c = 0; c < 4; ++c)
                    acc[a][c] += xa[a] * wa[c];
        }
        __syncthreads();
    }

    const float4 av = *(const float4*)(a_src + tx * 4);
    const float4 dv = *(const float4*)(a_dst + tx * 4);
#pragma unroll
    for (int a = 0; a < 4; ++a) {
        int n = n0 + ty * 4 + a;
        uint2 pk;
        pk.x = bf16_rne(acc[a][0]) | (bf16_rne(acc[a][1]) << 16);
        pk.y = bf16_rne(acc[a][2]) | (bf16_rne(acc[a][3]) << 16);
        if (n < N)
            *(uint2*)(h_bf + (size_t)n * 64 + tx * 4) = pk;
        float e1 = acc[a][0] * av.x + acc[a][1] * av.y + acc[a][2] * av.z + acc[a][3] * av.w;
        float e2 = acc[a][0] * dv.x + acc[a][1] * dv.y + acc[a][2] * dv.z + acc[a][3] * dv.w;
        e1 += __shfl_xor(e1, 1, 64); e2 += __shfl_xor(e2, 1, 64);
        e1 += __shfl_xor(e1, 2, 64); e2 += __shfl_xor(e2, 2, 64);
        if ((tx & 3) == 0 && n < N) {
            es[(size_t)n * 4 + (tx >> 2)] = e1;
            ed[(size_t)n * 4 + (tx >> 2)] = e2;
        }
    }
}

// ---------------- CSR build: LDS bucket sort (no global atomics) ----------------
__global__ __launch_bounds__(256) void bucket_hist(const int* __restrict__ dst,
                                                   int* __restrict__ hist_g,
                                                   int E, int Etot, int NBUCK, int nIter) {
    __shared__ int hist[512];
    int blk = blockIdx.x, tid = threadIdx.x;
    for (int i = tid; i < NBUCK; i += 256) hist[i] = 0;
    __syncthreads();
    int base = blk * nIter * 256;
    for (int i = 0; i < nIter; ++i) {
        int e = base + i * 256 + tid;
        if (e < Etot) {
            int d = (e < E) ? dst[e] : e - E;
            atomicAdd(&hist[d >> BSH], 1);
        }
    }
    __syncthreads();
    for (int i = tid; i < NBUCK; i += 256) hist_g[(size_t)blk * NBUCK + i] = hist[i];
}

__global__ __launch_bounds__(256) void bucket_scan_blocks(int* __restrict__ hist_g,
                                                          int* __restrict__ tot,
                                                          int NBUCK, int NBLK) {
    __shared__ int s[256];
    int b = blockIdx.x, tid = threadIdx.x;
    int v = (tid < NBLK) ? hist_g[(size_t)tid * NBUCK + b] : 0;
    s[tid] = v; __syncthreads();
#pragma unroll
    for (int off = 1; off < 256; off <<= 1) {
        int t = (tid >= off) ? s[tid - off] : 0;
        __syncthreads();
        s[tid] += t;
        __syncthreads();
    }
    if (tid < NBLK) hist_g[(size_t)tid * NBUCK + b] = s[tid] - v;  // exclusive
    if (tid == 255) tot[b] = s[255];
}

__global__ void bucket_scan_tot(const int* __restrict__ tot, int* __restrict__ bbase,
                                int* __restrict__ offs, int NBUCK, int Etot, int N) {
    __shared__ int s[512];
    int tid = threadIdx.x;
    int v = (tid < NBUCK) ? tot[tid] : 0;
    s[tid] = v; __syncthreads();
#pragma unroll
    for (int off = 1; off < 512; off <<= 1) {
        int t = (tid >= off) ? s[tid - off] : 0;
        __syncthreads();
        s[tid] += t;
        __syncthreads();
    }
    if (tid < NBUCK) bbase[tid] = s[tid] - v;
    if (tid == 0) offs[N] = Etot;
}

__global__ __launch_bounds__(256) void bucket_scatter(const int* __restrict__ src,
                                                      const int* __restrict__ dst,
                                                      const int* __restrict__ hist_g,
                                                      const int* __restrict__ bbase,
                                                      unsigned int* __restrict__ bbuf,
                                                      int E, int Etot, int NBUCK, int nIter) {
    __shared__ int lcur[512];
    int blk = blockIdx.x, tid = threadIdx.x;
    for (int i = tid; i < NBUCK; i += 256)
        lcur[i] = bbase[i] + hist_g[(size_t)blk * NBUCK + i];
    __syncthreads();
    int base = blk * nIter * 256;
    for (int i = 0; i < nIter; ++i) {
        int e = base + i * 256 + tid;
        if (e >= Etot) continue;
        int s, d;
        if (e < E) { s = src[e]; d = dst[e]; } else { s = d = e - E; }
        int pos = atomicAdd(&lcur[d >> BSH], 1);
        bbuf[pos] = (unsigned)s | ((unsigned)(d & ((1 << BSH) - 1)) << 24);
    }
}

__global__ __launch_bounds__(256) void bucket_build(const unsigned int* __restrict__ bbuf,
                                                    const int* __restrict__ bbase,
                                                    const int* __restrict__ tot,
                                                    int* __restrict__ col,
                                                    int* __restrict__ offs,
                                                    int N, int NBUCK) {
    __shared__ int cnt[256], lcur[256], s[256];
    __shared__ int ordered[CAPB];
    int b = blockIdx.x, tid = threadIdx.x;
    int bb = bbase[b];
    int t = tot[b];
    int n0 = b << BSH;
    cnt[tid] = 0;
    __syncthreads();
    for (int i = tid; i < t; i += 256) {
        unsigned v = bbuf[bb + i];
        atomicAdd(&cnt[v >> 24], 1);
    }
    __syncthreads();
    int c = cnt[tid];
    s[tid] = c; __syncthreads();
#pragma unroll
    for (int off = 1; off < 256; off <<= 1) {
        int tt = (tid >= off) ? s[tid - off] : 0;
        __syncthreads();
        s[tid] += tt;
        __syncthreads();
    }
    int ex = s[tid] - c;
    lcur[tid] = ex;
    if (n0 + tid < N) offs[n0 + tid] = bb + ex;
    __syncthreads();
    if (t <= CAPB) {
        for (int i = tid; i < t; i += 256) {
            unsigned v = bbuf[bb + i];
            int pos = atomicAdd(&lcur[v >> 24], 1);
            ordered[pos] = (int)(v & 0xFFFFFFu);
        }
        __syncthreads();
        for (int i = tid; i < t; i += 256) col[bb + i] = ordered[i];
    } else {  // fallback (never expected for near-uniform dst)
        for (int i = tid; i < t; i += 256) {
            unsigned v = bbuf[bb + i];
            int pos = atomicAdd(&lcur[v >> 24], 1);
            col[bb + pos] = (int)(v & 0xFFFFFFu);
        }
    }
}

// ---------------- fused gather: 8 edges/wave-iter, uint4 bf16 (16B/lane) -------
// lane = (eslot<<3) | co ; eslot in [0,8) handles edge j+eslot; co in [0,8)
// handles channels [8co,8co+8); head = co>>1. Softmax in no-max form (logits
// bounded); epilogue: /denom + bias + ELU; FINAL fuses the fc dot product.
template <bool FINAL>
__global__ __launch_bounds__(256) void gat_gather8(const int* __restrict__ offs,
                                                   const int* __restrict__ col,
                                                   const float* __restrict__ es,
                                                   const float* __restrict__ ed,
                                                   const unsigned short* __restrict__ h_bf,
                                                   const float* __restrict__ b,
                                                   const float* __restrict__ fcw,
                                                   const float* __restrict__ fcb,
                                                   float* __restrict__ xo, int N) {
    int w = (blockIdx.x * 256 + threadIdx.x) >> 6;
    if (w >= N) return;
    const int lane = threadIdx.x & 63;
    const int eslot = lane >> 3, co = lane & 7, hd = co >> 1;
    const int beg = offs[w];
    const int cnt = offs[w + 1] - beg;
    const float edv = ed[(size_t)w * 4 + hd];

    float acc0 = 0.f, acc1 = 0.f, acc2 = 0.f, acc3 = 0.f;
    float acc4 = 0.f, acc5 = 0.f, acc6 = 0.f, acc7 = 0.f;
    float l = 0.f;
    for (int j = 0; j < cnt; j += 8) {
        int k = j + eslot;
        bool valid = k < cnt;
        int s = valid ? col[beg + k] : 0;
        float a = es[(size_t)s * 4 + hd] + edv;
        a = a > 0.f ? a : NEG_SLOPE * a;
        float p = valid ? __expf(a) : 0.f;
        uint4 hv = *(const uint4*)(h_bf + (size_t)s * 64 + co * 8);
        acc0 += p * bf_lo(hv.x); acc1 += p * bf_hi(hv.x);
        acc2 += p * bf_lo(hv.y); acc3 += p * bf_hi(hv.y);
        acc4 += p * bf_lo(hv.z); acc5 += p * bf_hi(hv.z);
        acc6 += p * bf_lo(hv.w); acc7 += p * bf_hi(hv.w);
        l += p;
    }
    // reduce across the 8 eslots (fixed co): masks 8,16,32
#pragma unroll
    for (int m = 8; m <= 32; m <<= 1) {
        acc0 += __shfl_xor(acc0, m, 64); acc1 += __shfl_xor(acc1, m, 64);
        acc2 += __shfl_xor(acc2, m, 64); acc3 += __shfl_xor(acc3, m, 64);
        acc4 += __shfl_xor(acc4, m, 64); acc5 += __shfl_xor(acc5, m, 64);
        acc6 += __shfl_xor(acc6, m, 64); acc7 += __shfl_xor(acc7, m, 64);
        l    += __shfl_xor(l, m, 64);
    }
    const float inv = 1.f / (l + 1e-16f);
    const float4 bv0 = *(const float4*)(b + co * 8);
    const float4 bv1 = *(const float4*)(b + co * 8 + 4);
    float v0 = acc0 * inv + bv0.x, v1 = acc1 * inv + bv0.y;
    float v2 = acc2 * inv + bv0.z, v3 = acc3 * inv + bv0.w;
    float v4 = acc4 * inv + bv1.x, v5 = acc5 * inv + bv1.y;
    float v6 = acc6 * inv + bv1.z, v7 = acc7 * inv + bv1.w;
    v0 = v0 > 0.f ? v0 : __expf(v0) - 1.f;
    v1 = v1 > 0.f ? v1 : __expf(v1) - 1.f;
    v2 = v2 > 0.f ? v2 : __expf(v2) - 1.f;
    v3 = v3 > 0.f ? v3 : __expf(v3) - 1.f;
    v4 = v4 > 0.f ? v4 : __expf(v4) - 1.f;
    v5 = v5 > 0.f ? v5 : __expf(v5) - 1.f;
    v6 = v6 > 0.f ? v6 : __expf(v6) - 1.f;
    v7 = v7 > 0.f ? v7 : __expf(v7) - 1.f;
    if (FINAL) {
        const float4 fw0 = *(const float4*)(fcw + co * 8);
        const float4 fw1 = *(const float4*)(fcw + co * 8 + 4);
        float t = v0 * fw0.x + v1 * fw0.y + v2 * fw0.z + v3 * fw0.w +
                  v4 * fw1.x + v5 * fw1.y + v6 * fw1.z + v7 * fw1.w;
#pragma unroll
        for (int m = 1; m <= 4; m <<= 1) t += __shfl_xor(t, m, 64);
        if (lane == 0) xo[w] = t + fcb[0];
    } else {
        if (lane < 8) {
            *(float4*)(xo + (size_t)w * 64 + co * 8)     = make_float4(v0, v1, v2, v3);
            *(float4*)(xo + (size_t)w * 64 + co * 8 + 4) = make_float4(v4, v5, v6, v7);
        }
    }
}

extern "C" void kernel_launch(void* const* d_in, const int* in_sizes, int n_in,
                              void* d_out, int out_size, void* d_ws, size_t ws_size,
                              hipStream_t stream) {
    const float* x   = (const float*)d_in[0];
    const int*   ei  = (const int*)d_in[1];
    const float* w1  = (const float*)d_in[2];
    const float* as1 = (const float*)d_in[3];
    const float* ad1 = (const float*)d_in[4];
    const float* b1  = (const float*)d_in[5];
    const float* w2  = (const float*)d_in[6];
    const float* as2 = (const float*)d_in[7];
    const float* ad2 = (const float*)d_in[8];
    const float* b2  = (const float*)d_in[9];
    const float* fcw = (const float*)d_in[10];
    const float* fcb = (const float*)d_in[11];
    float* out = (float*)d_out;

    const int N = in_sizes[0] / 128;  // 100000
    const int E = in_sizes[1] / 2;    // 1600000
    const int Etot = E + N;
    const int* src = ei;
    const int* dst = ei + E;

    const int NBUCK = (N + 255) >> BSH;          // 391 (<=512)
    int CHe = 8192;
    while ((Etot + CHe - 1) / CHe > 256) CHe *= 2;
    const int NBLK = (Etot + CHe - 1) / CHe;     // 208 (<=256)
    const int nIter = CHe / 256;

    char* p = (char*)d_ws;
    unsigned short* h_bf = (unsigned short*)p;  p += (size_t)N * 64 * 2;
    float* x2    = (float*)p;  p += (size_t)N * 64 * 4;
    float* es    = (float*)p;  p += (size_t)N * 4 * 4;
    float* ed    = (float*)p;  p += (size_t)N * 4 * 4;
    int* offs    = (int*)p;    p += (size_t)(N + 1) * 4;
    int* tot     = (int*)p;    p += (size_t)NBUCK * 4;
    int* bbase   = (int*)p;    p += (size_t)NBUCK * 4;
    int* hist_g  = (int*)p;    p += (size_t)NBLK * NBUCK * 4;
    int* col     = (int*)p;    p += (size_t)Etot * 4;
    unsigned int* bbuf = (unsigned int*)x2;      // alias: x2 unused until gather L1

    dim3 blk(256);
    const int gN64t = (N + 63) / 64;
    const int gW   = (N * 64 + 255) / 256;

    // ---- CSR build (LDS bucket sort; shared by both layers) ----
    bucket_hist<<<NBLK, blk, 0, stream>>>(dst, hist_g, E, Etot, NBUCK, nIter);
    bucket_scan_blocks<<<NBUCK, blk, 0, stream>>>(hist_g, tot, NBUCK, NBLK);
    bucket_scan_tot<<<1, 512, 0, stream>>>(tot, bbase, offs, NBUCK, Etot, N);
    bucket_scatter<<<NBLK, blk, 0, stream>>>(src, dst, hist_g, bbase, bbuf, E, Etot, NBUCK, nIter);
    bucket_build<<<NBUCK, blk, 0, stream>>>(bbuf, bbase, tot, col, offs, N, NBUCK);

    // ---- layer 1 ----
    gemm_tile<128><<<gN64t, blk, 0, stream>>>(x, w1, as1, ad1, h_bf, es, ed, N);
    gat_gather8<false><<<gW, blk, 0, stream>>>(offs, col, es, ed, h_bf, b1, nullptr, nullptr, x2, N);

    // ---- layer 2 ----
    gemm_tile<64><<<gN64t, blk, 0, stream>>>(x2, w2, as2, ad2, h_bf, es, ed, N);
    gat_gather8<true><<<gW, blk, 0, stream>>>(offs, col, es, ed, h_bf, b2, fcw, fcb, out, N);
}

// Round 8
// 213.984 us; speedup vs baseline: 62.7867x; 1.0524x over previous
//
#include <hip/hip_runtime.h>
#include <math.h>

#define NEG_SLOPE 0.2f
#define BSH 8              // 256 nodes per bucket
#define CAPB 6144          // phase-B LDS capacity (entries); mean ~4352

__device__ __forceinline__ unsigned bf16_rne(float x) {
    unsigned u = __float_as_uint(x);
    return (u + 0x7FFFu + ((u >> 16) & 1u)) >> 16;
}
__device__ __forceinline__ float bf_lo(unsigned u) { return __uint_as_float(u << 16); }
__device__ __forceinline__ float bf_hi(unsigned u) { return __uint_as_float(u & 0xFFFF0000u); }

// ---------------- dense h = x @ W^T, fused attn coefs, bf16 h output -----------
// 64x64 tile per block, 4x4 per thread, k-major LDS staging.
// Outputs: h_bf[n][64] bf16; es/ed[n][4] fp32 (dot of h row with a_src/a_dst).
template <int K>
__global__ __launch_bounds__(256) void gemm_tile(const float* __restrict__ x,
                                                 const float* __restrict__ W,
                                                 const float* __restrict__ a_src,
                                                 const float* __restrict__ a_dst,
                                                 unsigned short* __restrict__ h_bf,
                                                 float* __restrict__ es,
                                                 float* __restrict__ ed,
                                                 int N) {
    constexpr int CK = 32;
    __shared__ float xs[CK][68];
    __shared__ float ws[CK][68];
    const int tid = threadIdx.x;
    const int n0 = blockIdx.x * 64;
    const int tx = tid & 15, ty = tid >> 4;

    float acc[4][4] = {};

    for (int k0 = 0; k0 < K; k0 += CK) {
#pragma unroll
        for (int i = 0; i < 2; ++i) {
            int slot = tid + i * 256;
            int nl = slot >> 3;
            int kq = slot & 7;
            int n = n0 + nl;
            float4 v = (n < N) ? *(const float4*)(x + (size_t)n * K + k0 + kq * 4)
                               : make_float4(0.f, 0.f, 0.f, 0.f);
            xs[kq * 4 + 0][nl] = v.x; xs[kq * 4 + 1][nl] = v.y;
            xs[kq * 4 + 2][nl] = v.z; xs[kq * 4 + 3][nl] = v.w;
            float4 wv = *(const float4*)(W + (size_t)nl * K + k0 + kq * 4);
            ws[kq * 4 + 0][nl] = wv.x; ws[kq * 4 + 1][nl] = wv.y;
            ws[kq * 4 + 2][nl] = wv.z; ws[kq * 4 + 3][nl] = wv.w;
        }
        __syncthreads();
#pragma unroll
        for (int k = 0; k < CK; ++k) {
            float4 xv = *(const float4*)(&xs[k][ty * 4]);
            float4 wv = *(const float4*)(&ws[k][tx * 4]);
            float xa[4] = {xv.x, xv.y, xv.z, xv.w};
            float wa[4] = {wv.x, wv.y, wv.z, wv.w};
#pragma unroll
            for (int a = 0; a < 4; ++a)
#pragma unroll
                for (int c = 0; c < 4; ++c)
                    acc[a][c] += xa[a] * wa[c];
        }
        __syncthreads();
    }

    const float4 av = *(const float4*)(a_src + tx * 4);
    const float4 dv = *(const float4*)(a_dst + tx * 4);
#pragma unroll
    for (int a = 0; a < 4; ++a) {
        int n = n0 + ty * 4 + a;
        uint2 pk;
        pk.x = bf16_rne(acc[a][0]) | (bf16_rne(acc[a][1]) << 16);
        pk.y = bf16_rne(acc[a][2]) | (bf16_rne(acc[a][3]) << 16);
        if (n < N)
            *(uint2*)(h_bf + (size_t)n * 64 + tx * 4) = pk;
        float e1 = acc[a][0] * av.x + acc[a][1] * av.y + acc[a][2] * av.z + acc[a][3] * av.w;
        float e2 = acc[a][0] * dv.x + acc[a][1] * dv.y + acc[a][2] * dv.z + acc[a][3] * dv.w;
        e1 += __shfl_xor(e1, 1, 64); e2 += __shfl_xor(e2, 1, 64);
        e1 += __shfl_xor(e1, 2, 64); e2 += __shfl_xor(e2, 2, 64);
        if ((tx & 3) == 0 && n < N) {
            es[(size_t)n * 4 + (tx >> 2)] = e1;
            ed[(size_t)n * 4 + (tx >> 2)] = e2;
        }
    }
}

// ---------------- CSR build: LDS bucket sort (no global atomics) ----------------
__global__ __launch_bounds__(256) void bucket_hist(const int* __restrict__ dst,
                                                   int* __restrict__ hist_g,
                                                   int E, int Etot, int NBUCK, int nIter) {
    __shared__ int hist[512];
    int blk = blockIdx.x, tid = threadIdx.x;
    for (int i = tid; i < NBUCK; i += 256) hist[i] = 0;
    __syncthreads();
    int base = blk * nIter * 256;
    for (int i = 0; i < nIter; ++i) {
        int e = base + i * 256 + tid;
        if (e < Etot) {
            int d = (e < E) ? dst[e] : e - E;
            atomicAdd(&hist[d >> BSH], 1);
        }
    }
    __syncthreads();
    for (int i = tid; i < NBUCK; i += 256) hist_g[(size_t)blk * NBUCK + i] = hist[i];
}

__global__ __launch_bounds__(256) void bucket_scan_blocks(int* __restrict__ hist_g,
                                                          int* __restrict__ tot,
                                                          int NBUCK, int NBLK) {
    __shared__ int s[256];
    int b = blockIdx.x, tid = threadIdx.x;
    int v = (tid < NBLK) ? hist_g[(size_t)tid * NBUCK + b] : 0;
    s[tid] = v; __syncthreads();
#pragma unroll
    for (int off = 1; off < 256; off <<= 1) {
        int t = (tid >= off) ? s[tid - off] : 0;
        __syncthreads();
        s[tid] += t;
        __syncthreads();
    }
    if (tid < NBLK) hist_g[(size_t)tid * NBUCK + b] = s[tid] - v;  // exclusive
    if (tid == 255) tot[b] = s[255];
}

__global__ void bucket_scan_tot(const int* __restrict__ tot, int* __restrict__ bbase,
                                int* __restrict__ offs, int NBUCK, int Etot, int N) {
    __shared__ int s[512];
    int tid = threadIdx.x;
    int v = (tid < NBUCK) ? tot[tid] : 0;
    s[tid] = v; __syncthreads();
#pragma unroll
    for (int off = 1; off < 512; off <<= 1) {
        int t = (tid >= off) ? s[tid - off] : 0;
        __syncthreads();
        s[tid] += t;
        __syncthreads();
    }
    if (tid < NBUCK) bbase[tid] = s[tid] - v;
    if (tid == 0) offs[N] = Etot;
}

__global__ __launch_bounds__(256) void bucket_scatter(const int* __restrict__ src,
                                                      const int* __restrict__ dst,
                                                      const int* __restrict__ hist_g,
                                                      const int* __restrict__ bbase,
                                                      unsigned int* __restrict__ bbuf,
                                                      int E, int Etot, int NBUCK, int nIter) {
    __shared__ int lcur[512];
    int blk = blockIdx.x, tid = threadIdx.x;
    for (int i = tid; i < NBUCK; i += 256)
        lcur[i] = bbase[i] + hist_g[(size_t)blk * NBUCK + i];
    __syncthreads();
    int base = blk * nIter * 256;
    for (int i = 0; i < nIter; ++i) {
        int e = base + i * 256 + tid;
        if (e >= Etot) continue;
        int s, d;
        if (e < E) { s = src[e]; d = dst[e]; } else { s = d = e - E; }
        int pos = atomicAdd(&lcur[d >> BSH], 1);
        bbuf[pos] = (unsigned)s | ((unsigned)(d & ((1 << BSH) - 1)) << 24);
    }
}

__global__ __launch_bounds__(256) void bucket_build(const unsigned int* __restrict__ bbuf,
                                                    const int* __restrict__ bbase,
                                                    const int* __restrict__ tot,
                                                    int* __restrict__ col,
                                                    int* __restrict__ offs,
                                                    int N, int NBUCK) {
    __shared__ int cnt[256], lcur[256], s[256];
    __shared__ int ordered[CAPB];
    int b = blockIdx.x, tid = threadIdx.x;
    int bb = bbase[b];
    int t = tot[b];
    int n0 = b << BSH;
    cnt[tid] = 0;
    __syncthreads();
    for (int i = tid; i < t; i += 256) {
        unsigned v = bbuf[bb + i];
        atomicAdd(&cnt[v >> 24], 1);
    }
    __syncthreads();
    int c = cnt[tid];
    s[tid] = c; __syncthreads();
#pragma unroll
    for (int off = 1; off < 256; off <<= 1) {
        int tt = (tid >= off) ? s[tid - off] : 0;
        __syncthreads();
        s[tid] += tt;
        __syncthreads();
    }
    int ex = s[tid] - c;
    lcur[tid] = ex;
    if (n0 + tid < N) offs[n0 + tid] = bb + ex;
    __syncthreads();
    if (t <= CAPB) {
        for (int i = tid; i < t; i += 256) {
            unsigned v = bbuf[bb + i];
            int pos = atomicAdd(&lcur[v >> 24], 1);
            ordered[pos] = (int)(v & 0xFFFFFFu);
        }
        __syncthreads();
        for (int i = tid; i < t; i += 256) col[bb + i] = ordered[i];
    } else {  // fallback (never expected for near-uniform dst)
        for (int i = tid; i < t; i += 256) {
            unsigned v = bbuf[bb + i];
            int pos = atomicAdd(&lcur[v >> 24], 1);
            col[bb + pos] = (int)(v & 0xFFFFFFu);
        }
    }
}

// ---------------- fused gather: upfront col load + 8 edges/iter ----------------
// lane = (eslot<<3) | co ; eslot in [0,8); co in [0,8) covers channels
// [8co,8co+8); head = co>>1. The wave's whole edge list (cnt<=64, which holds
// for all nodes at mean degree ~17) is loaded with ONE coalesced col read;
// per-iteration src indices come from register shfl, so es/h loads of ALL
// iterations are address-ready immediately -> deep MLP. Softmax in no-max form.
template <bool FINAL>
__global__ __launch_bounds__(256) void gat_gather8(const int* __restrict__ offs,
                                                   const int* __restrict__ col,
                                                   const float* __restrict__ es,
                                                   const float* __restrict__ ed,
                                                   const unsigned short* __restrict__ h_bf,
                                                   const float* __restrict__ b,
                                                   const float* __restrict__ fcw,
                                                   const float* __restrict__ fcb,
                                                   float* __restrict__ xo, int N) {
    int w = (blockIdx.x * 256 + threadIdx.x) >> 6;
    if (w >= N) return;
    const int lane = threadIdx.x & 63;
    const int eslot = lane >> 3, co = lane & 7, hd = co >> 1;
    const int beg = offs[w];
    const int cnt = offs[w + 1] - beg;
    const float edv = ed[(size_t)w * 4 + hd];

    // whole edge list in registers (cnt >= 1 always: self-loop)
    const int cnt64 = min(cnt, 64);
    int myCol = col[beg + min(lane, cnt64 - 1)];

    float acc0 = 0.f, acc1 = 0.f, acc2 = 0.f, acc3 = 0.f;
    float acc4 = 0.f, acc5 = 0.f, acc6 = 0.f, acc7 = 0.f;
    float l = 0.f;
    for (int j = 0; j < cnt64; j += 8) {
        int k = j + eslot;                 // < 64 always
        bool valid = k < cnt64;
        int s = __shfl(myCol, k, 64);      // clamped for invalid k -> harmless
        float a = es[(size_t)s * 4 + hd] + edv;
        a = a > 0.f ? a : NEG_SLOPE * a;
        float p = valid ? __expf(a) : 0.f;
        uint4 hv = *(const uint4*)(h_bf + (size_t)s * 64 + co * 8);
        acc0 += p * bf_lo(hv.x); acc1 += p * bf_hi(hv.x);
        acc2 += p * bf_lo(hv.y); acc3 += p * bf_hi(hv.y);
        acc4 += p * bf_lo(hv.z); acc5 += p * bf_hi(hv.z);
        acc6 += p * bf_lo(hv.w); acc7 += p * bf_hi(hv.w);
        l += p;
    }
    // slow path for pathological high-degree nodes (cnt > 64)
    for (int j = 64; j < cnt; j += 8) {
        int k = j + eslot;
        bool valid = k < cnt;
        int s = valid ? col[beg + k] : 0;
        float a = es[(size_t)s * 4 + hd] + edv;
        a = a > 0.f ? a : NEG_SLOPE * a;
        float p = valid ? __expf(a) : 0.f;
        uint4 hv = *(const uint4*)(h_bf + (size_t)s * 64 + co * 8);
        acc0 += p * bf_lo(hv.x); acc1 += p * bf_hi(hv.x);
        acc2 += p * bf_lo(hv.y); acc3 += p * bf_hi(hv.y);
        acc4 += p * bf_lo(hv.z); acc5 += p * bf_hi(hv.z);
        acc6 += p * bf_lo(hv.w); acc7 += p * bf_hi(hv.w);
        l += p;
    }
    // reduce across the 8 eslots (fixed co): masks 8,16,32
#pragma unroll
    for (int m = 8; m <= 32; m <<= 1) {
        acc0 += __shfl_xor(acc0, m, 64); acc1 += __shfl_xor(acc1, m, 64);
        acc2 += __shfl_xor(acc2, m, 64); acc3 += __shfl_xor(acc3, m, 64);
        acc4 += __shfl_xor(acc4, m, 64); acc5 += __shfl_xor(acc5, m, 64);
        acc6 += __shfl_xor(acc6, m, 64); acc7 += __shfl_xor(acc7, m, 64);
        l    += __shfl_xor(l, m, 64);
    }
    const float inv = 1.f / (l + 1e-16f);
    const float4 bv0 = *(const float4*)(b + co * 8);
    const float4 bv1 = *(const float4*)(b + co * 8 + 4);
    float v0 = acc0 * inv + bv0.x, v1 = acc1 * inv + bv0.y;
    float v2 = acc2 * inv + bv0.z, v3 = acc3 * inv + bv0.w;
    float v4 = acc4 * inv + bv1.x, v5 = acc5 * inv + bv1.y;
    float v6 = acc6 * inv + bv1.z, v7 = acc7 * inv + bv1.w;
    v0 = v0 > 0.f ? v0 : __expf(v0) - 1.f;
    v1 = v1 > 0.f ? v1 : __expf(v1) - 1.f;
    v2 = v2 > 0.f ? v2 : __expf(v2) - 1.f;
    v3 = v3 > 0.f ? v3 : __expf(v3) - 1.f;
    v4 = v4 > 0.f ? v4 : __expf(v4) - 1.f;
    v5 = v5 > 0.f ? v5 : __expf(v5) - 1.f;
    v6 = v6 > 0.f ? v6 : __expf(v6) - 1.f;
    v7 = v7 > 0.f ? v7 : __expf(v7) - 1.f;
    if (FINAL) {
        const float4 fw0 = *(const float4*)(fcw + co * 8);
        const float4 fw1 = *(const float4*)(fcw + co * 8 + 4);
        float t = v0 * fw0.x + v1 * fw0.y + v2 * fw0.z + v3 * fw0.w +
                  v4 * fw1.x + v5 * fw1.y + v6 * fw1.z + v7 * fw1.w;
#pragma unroll
        for (int m = 1; m <= 4; m <<= 1) t += __shfl_xor(t, m, 64);
        if (lane == 0) xo[w] = t + fcb[0];
    } else {
        if (lane < 8) {
            *(float4*)(xo + (size_t)w * 64 + co * 8)     = make_float4(v0, v1, v2, v3);
            *(float4*)(xo + (size_t)w * 64 + co * 8 + 4) = make_float4(v4, v5, v6, v7);
        }
    }
}

extern "C" void kernel_launch(void* const* d_in, const int* in_sizes, int n_in,
                              void* d_out, int out_size, void* d_ws, size_t ws_size,
                              hipStream_t stream) {
    const float* x   = (const float*)d_in[0];
    const int*   ei  = (const int*)d_in[1];
    const float* w1  = (const float*)d_in[2];
    const float* as1 = (const float*)d_in[3];
    const float* ad1 = (const float*)d_in[4];
    const float* b1  = (const float*)d_in[5];
    const float* w2  = (const float*)d_in[6];
    const float* as2 = (const float*)d_in[7];
    const float* ad2 = (const float*)d_in[8];
    const float* b2  = (const float*)d_in[9];
    const float* fcw = (const float*)d_in[10];
    const float* fcb = (const float*)d_in[11];
    float* out = (float*)d_out;

    const int N = in_sizes[0] / 128;  // 100000
    const int E = in_sizes[1] / 2;    // 1600000
    const int Etot = E + N;
    const int* src = ei;
    const int* dst = ei + E;

    const int NBUCK = (N + 255) >> BSH;          // 391 (<=512)
    int CHe = 8192;
    while ((Etot + CHe - 1) / CHe > 256) CHe *= 2;
    const int NBLK = (Etot + CHe - 1) / CHe;     // 208 (<=256)
    const int nIter = CHe / 256;

    char* p = (char*)d_ws;
    unsigned short* h_bf = (unsigned short*)p;  p += (size_t)N * 64 * 2;
    float* x2    = (float*)p;  p += (size_t)N * 64 * 4;
    float* es    = (float*)p;  p += (size_t)N * 4 * 4;
    float* ed    = (float*)p;  p += (size_t)N * 4 * 4;
    int* offs    = (int*)p;    p += (size_t)(N + 1) * 4;
    int* tot     = (int*)p;    p += (size_t)NBUCK * 4;
    int* bbase   = (int*)p;    p += (size_t)NBUCK * 4;
    int* hist_g  = (int*)p;    p += (size_t)NBLK * NBUCK * 4;
    int* col     = (int*)p;    p += (size_t)Etot * 4;
    unsigned int* bbuf = (unsigned int*)x2;      // alias: x2 unused until gather L1

    dim3 blk(256);
    const int gN64t = (N + 63) / 64;
    const int gW   = (N * 64 + 255) / 256;

    // ---- CSR build (LDS bucket sort; shared by both layers) ----
    bucket_hist<<<NBLK, blk, 0, stream>>>(dst, hist_g, E, Etot, NBUCK, nIter);
    bucket_scan_blocks<<<NBUCK, blk, 0, stream>>>(hist_g, tot, NBUCK, NBLK);
    bucket_scan_tot<<<1, 512, 0, stream>>>(tot, bbase, offs, NBUCK, Etot, N);
    bucket_scatter<<<NBLK, blk, 0, stream>>>(src, dst, hist_g, bbase, bbuf, E, Etot, NBUCK, nIter);
    bucket_build<<<NBUCK, blk, 0, stream>>>(bbuf, bbase, tot, col, offs, N, NBUCK);

    // ---- layer 1 ----
    gemm_tile<128><<<gN64t, blk, 0, stream>>>(x, w1, as1, ad1, h_bf, es, ed, N);
    gat_gather8<false><<<gW, blk, 0, stream>>>(offs, col, es, ed, h_bf, b1, nullptr, nullptr, x2, N);

    // ---- layer 2 ----
    gemm_tile<64><<<gN64t, blk, 0, stream>>>(x2, w2, as2, ad2, h_bf, es, ed, N);
    gat_gather8<true><<<gW, blk, 0, stream>>>(offs, col, es, ed, h_bf, b2, fcw, fcb, out, N);
}